// Round 12
// baseline (3267.954 us; speedup 1.0000x reference)
//
#include <hip/hip_runtime.h>
#include <math.h>

#define PI_F 3.14159265358979323846f
typedef _Float16 f16;
typedef __attribute__((ext_vector_type(8))) _Float16 f16x8;
typedef __attribute__((ext_vector_type(4))) float f32x4;

__device__ __forceinline__ float siluf(float x){ return x / (1.f + expf(-x)); }
__device__ __forceinline__ float softplusf(float x){ return fmaxf(x,0.f) + log1pf(expf(-fabsf(x))); }
__device__ __forceinline__ void f2hl(float v, f16& hi, f16& lo){
  hi = (f16)v;
  lo = (f16)(v - (float)hi);
}

// ---------------- DFT band filtering ----------------
__global__ void k_dft_rows(const float* __restrict__ x, float* __restrict__ Tre, float* __restrict__ Tim){
  int v = threadIdx.x; int y = blockIdx.x; int b = blockIdx.y;
  __shared__ float cs[128], sn[128];
  float ang = -2.f*PI_F*(float)v/128.f;
  cs[v]=cosf(ang); sn[v]=sinf(ang);
  __syncthreads();
  const float* row = x + (b*128+y)*128;
  float re=0.f, im=0.f;
  for(int n=0;n<128;n++){ float xv=row[n]; int ph=(v*n)&127; re=fmaf(xv,cs[ph],re); im=fmaf(xv,sn[ph],im); }
  int o=(b*128+y)*128+v; Tre[o]=re; Tim[o]=im;
}
__global__ void k_dft_cols(const float* __restrict__ Tre, const float* __restrict__ Tim,
                           float* __restrict__ Fre, float* __restrict__ Fim){
  int v=threadIdx.x; int u=blockIdx.x; int b=blockIdx.y;
  __shared__ float cs[128], sn[128];
  float ang=-2.f*PI_F*(float)v/128.f; cs[v]=cosf(ang); sn[v]=sinf(ang);
  __syncthreads();
  float re=0.f,im=0.f;
  for(int y=0;y<128;y++){
    int ph=(u*y)&127; float c=cs[ph], s=sn[ph];
    int o=(b*128+y)*128+v;
    float tr=Tre[o], ti=Tim[o];
    re += tr*c - ti*s; im += tr*s + ti*c;
  }
  int o=(b*128+u)*128+v; Fre[o]=re; Fim[o]=im;
}
__global__ void k_idft_cols(const float* __restrict__ Fre,const float* __restrict__ Fim,
                            const float* __restrict__ mask, float* __restrict__ Gre,float* __restrict__ Gim){
  int v=threadIdx.x; int y=blockIdx.x; int m=blockIdx.y; int b=blockIdx.z;
  __shared__ float cs[128], sn[128];
  float ang=-2.f*PI_F*(float)v/128.f; cs[v]=cosf(ang); sn[v]=sinf(ang);
  __syncthreads();
  float re=0.f,im=0.f;
  for(int u=0;u<128;u++){
    int ph=(u*y)&127; float c=cs[ph], s=sn[ph];
    float w = mask[(m*128+u)*128+v];
    int o=(b*128+u)*128+v;
    float fr=Fre[o]*w, fi=Fim[o]*w;
    re += fr*c + fi*s;
    im += fi*c - fr*s;
  }
  int o=((b*3+m)*128+y)*128+v;
  Gre[o]=re*(1.f/128.f); Gim[o]=im*(1.f/128.f);
}
__global__ void k_idft_rows(const float* __restrict__ Gre,const float* __restrict__ Gim, float* __restrict__ xf){
  int xc=threadIdx.x; int y=blockIdx.x; int m=blockIdx.y; int b=blockIdx.z;
  __shared__ float cs[128], sn[128];
  float ang=-2.f*PI_F*(float)xc/128.f; cs[xc]=cosf(ang); sn[xc]=sinf(ang);
  __syncthreads();
  float re=0.f;
  const float* gr=Gre+((b*3+m)*128+y)*128;
  const float* gi=Gim+((b*3+m)*128+y)*128;
  for(int v=0;v<128;v++){
    int ph=(v*xc)&127;
    re += gr[v]*cs[ph] + gi[v]*sn[ph];
  }
  xf[((b*3+m)*128+y)*128+xc] = re*(1.f/128.f);
}

// ---------------- batched weight conversion (12 entries: conv_ig + up only) ----------------
#define NWD 12
struct WAll {
  const float* src[NWD];
  int N[NWD], Kp[NWD], up[NWD], ci[NWD], cip[NWD];
  int cum[NWD+1];
};
__global__ void k_wcvt_all(WAll d, int total, f16* __restrict__ bh, f16* __restrict__ bl){
  int gid = blockIdx.x*256 + threadIdx.x;
  if (gid >= total) return;
  int li = gid; const float* src = d.src[0];
  int N=d.N[0], Kp=d.Kp[0], up=d.up[0], Ci=d.ci[0], cip=d.cip[0];
  #pragma unroll
  for (int j=1;j<NWD;j++){
    if (gid >= d.cum[j]){
      li = gid - d.cum[j]; src=d.src[j]; N=d.N[j];Kp=d.Kp[j];up=d.up[j];Ci=d.ci[j];cip=d.cip[j];
    }
  }
  int n = li / Kp, k = li - n*Kp;
  float v = 0.f;
  if (up){
    int o = n>>2, p=(n>>1)&1, q=n&1;
    if (k < Ci) v = src[(((size_t)k*up + o)*2 + p)*2 + q];
  } else {
    int tap = k / cip, cc = k - tap*cip;
    if (n < N && cc < Ci) v = src[((size_t)n*Ci + cc)*9 + tap];
  }
  f16 h,l; f2hl(v,h,l);
  bh[gid]=h; bl[gid]=l;
}

// im2col for up-convs (f16 hi/lo): rows of M=B*H*W, k=ci
__global__ void k_im2col(const float* __restrict__ in1, int C1,
                         int H, int W, int wsh, int hwsh, int K, int Kp,
                         f16* __restrict__ Ah, f16* __restrict__ Al){
  int k = blockIdx.x*256 + threadIdx.x;
  int lm = blockIdx.y;
  if (k >= Kp) return;
  float val = 0.f;
  if (k < K){
    int m = lm;
    int b = m >> hwsh;
    int hw = m & ((1<<hwsh)-1);
    int y = hw >> wsh;
    int x = hw & (W-1);
    val = in1[(((size_t)b*C1 + k)*H + y)*W + x];
  }
  f16 h,l; f2hl(val,h,l);
  Ah[(size_t)lm*Kp + k] = h; Al[(size_t)lm*Kp + k] = l;
}

// im2col fp32 (3x3, pad 1), concat-aware: A[m*K + k], k = ci*9 + (ky*3+kx)
__global__ void k_im2col32(const float* __restrict__ in1, int C1,
                           const float* __restrict__ in2, int C2,
                           int H, int W, int wsh, int hwsh, int K,
                           float* __restrict__ A){
  int k = blockIdx.x*256 + threadIdx.x;
  int m = blockIdx.y;
  if (k >= K) return;
  int ci = k/9; int tt = k - ci*9;
  int dy = tt/3 - 1, dx = tt - (tt/3)*3 - 1;
  int b = m >> hwsh;
  int hw = m & ((1<<hwsh)-1);
  int y = (hw >> wsh) + dy;
  int x = (hw & (W-1)) + dx;
  float val = 0.f;
  if (y >= 0 && y < H && x >= 0 && x < W){
    val = (ci < C1) ? in1[(((size_t)b*C1 + ci)*H + y)*W + x]
                    : in2[(((size_t)b*C2 + (ci-C1))*H + y)*W + x];
  }
  A[(size_t)m*K + k] = val;
}

#define GLLDS(gp, ls) __builtin_amdgcn_global_load_lds( \
    (const __attribute__((address_space(1))) void*)(gp), \
    (__attribute__((address_space(3))) void*)(ls), 16, 0, 0)

// ---------------- implicit-GEMM conv3x3 (single-buffer input slab: 50KB LDS, 3 blocks/CU) ----------------
template<int NL>
__global__ __launch_bounds__(256) void k_conv_ig(
    const float* __restrict__ in1, int C1, const float* __restrict__ in2, int C2,
    const f16* __restrict__ Wh, const f16* __restrict__ Wl,
    const float* __restrict__ bias, float* __restrict__ out,
    int Co, int H, int W, int wsh, int hwsh, int Cip, int civ)
{
  __shared__ __align__(16) float smI[6464];     // single buffer: safe, writes happen post-MFMA-barrier
  __shared__ __align__(16) f16 smW[3*2*2048];
  const int HW = 1<<hwsh;
  const int tw = (W<64)?W:64;
  const int twsh = (wsh<6)?wsh:6;
  const int R = 64>>twsh;
  const int RT = R+2, TWD = tw+2;
  const int nspat = RT*TWD;
  const int CS = ((nspat+3)&~3)+2;
  const int total = nspat*32;
  const int nslab = Cip>>5;
  const int nsteps = 9*nslab;
  const int Kp = 9*Cip;

  int bn = blockIdx.y*64;
  int bm = blockIdx.x*64;
  int t = threadIdx.x;
  int lane = t&63, wv = t>>6;
  int wr = wv>>1, wc = wv&1;

  int b  = bm >> hwsh;
  int hw0 = bm & (HW-1);
  int y0 = hw0 >> wsh;
  int x0 = hw0 & (W-1);

  float bv[2][4];
  {
    int cb = bn + wr*32 + (lane>>4)*4;
    #pragma unroll
    for (int ri=0;ri<2;ri++)
      #pragma unroll
      for (int r=0;r<4;r++){
        int co = cb + ri*16 + r;
        bv[ri][r] = bias[co < Co ? co : Co-1];
      }
    asm volatile("s_waitcnt vmcnt(0)" ::: "memory");
  }

  int goff[NL], loff[NL];
  {
    int ci = 0, s = t;
    if (s >= nspat){ s -= nspat; ci++; }
    if (s >= nspat){ s -= nspat; ci++; }
    #pragma unroll
    for (int j=0;j<NL;j++){
      int rr_=0, sx=s;
      #pragma unroll
      for (int q=0;q<5;q++){ if (sx>=TWD){ sx-=TWD; rr_++; } }
      int gy = y0 - 1 + rr_;
      int gx = x0 - 1 + sx;
      int idx = t + j*256;
      bool intile = (idx < total);
      bool ok = intile && (ci < civ) && (gy>=0) && (gy<H) && (gx>=0) && (gx<W);
      goff[j] = ok ? (ci*HW + gy*W + gx) : -1;
      loff[j] = intile ? (ci*CS + rr_*TWD + sx) : -1;
      s += 256;
      if (s >= nspat){ s -= nspat; ci++; }
      if (s >= nspat){ s -= nspat; ci++; }
      if (s >= nspat){ s -= nspat; ci++; }
    }
  }

  int rr = lane >> 2;
  int cg = (lane & 3) ^ ((lane >> 3) & 3);
  size_t gW = (size_t)(bn + wv*16 + rr)*Kp + cg*8;
  int lb = wv*512;
  auto stage = [&](int bfi, int k0){
    GLLDS(Wh + gW + k0, &smW[(bfi*2+0)*2048 + lb]);
    GLLDS(Wl + gW + k0, &smW[(bfi*2+1)*2048 + lb]);
  };

  int rA = lane & 15, c = lane >> 4;
  int RW = wr*32 + rA; int sW = (RW>>1)&3;
  int offW = RW*32 + 8*(c ^ sW);
  int lp0 = wc*32 + rA, lp1 = lp0 + 16;
  int sid0 = ((lp0>>twsh)+1)*TWD + (lp0 & (tw-1)) + 1;
  int sid1 = ((lp1>>twsh)+1)*TWD + (lp1 & (tw-1)) + 1;
  int cbase = c*8*CS;
  int csj[8];
  #pragma unroll
  for (int j=0;j<8;j++) csj[j] = j*CS;

  auto srcptr = [&](int sl) -> const float* {
    int cbeg = sl*32;
    return (cbeg < C1) ? in1 + ((size_t)(b*C1 + cbeg))*HW
                       : in2 + ((size_t)(b*C2 + (cbeg - C1)))*HW;
  };

  float rin[NL];
  {
    const float* sp = srcptr(0);
    #pragma unroll
    for (int j=0;j<NL;j++) rin[j] = sp[goff[j] < 0 ? 0 : goff[j]];
  }
  stage(0, 0);
  stage(1, Cip);
  stage(2, 2*Cip);
  asm volatile("s_waitcnt vmcnt(6)" ::: "memory");
  #pragma unroll
  for (int j=0;j<NL;j++) if (loff[j] >= 0) smI[loff[j]] = (goff[j] < 0) ? 0.f : rin[j];
  asm volatile("s_waitcnt lgkmcnt(0)" ::: "memory");
  __builtin_amdgcn_s_barrier();
  asm volatile("" ::: "memory");
  if (nslab > 1){
    const float* sp = srcptr(1);
    #pragma unroll
    for (int j=0;j<NL;j++) rin[j] = sp[goff[j] < 0 ? 0 : goff[j]];
  }

  f32x4 zz = {0.f,0.f,0.f,0.f};
  f32x4 acc[2][2];
  acc[0][0]=zz; acc[0][1]=zz; acc[1][0]=zz; acc[1][1]=zz;

  int tcur = 0, scur = 0;
  int stp_t3 = 3, stp_s3 = 0;
  int bfi = 0;

  for (int step = 0; step < nsteps; ++step){
    if (tcur == 0 && step > 0){
      // all waves passed the post-MFMA barrier of the previous step -> safe to overwrite smI
      asm volatile("s_waitcnt vmcnt(6)" ::: "memory");
      #pragma unroll
      for (int j=0;j<NL;j++) if (loff[j] >= 0) smI[loff[j]] = (goff[j] < 0) ? 0.f : rin[j];
      asm volatile("s_waitcnt lgkmcnt(0)" ::: "memory");
      __builtin_amdgcn_s_barrier();
      asm volatile("" ::: "memory");
      if (scur + 1 < nslab){
        const float* sp = srcptr(scur+1);
        #pragma unroll
        for (int j=0;j<NL;j++) rin[j] = sp[goff[j] < 0 ? 0 : goff[j]];
      }
    }
    if (tcur < 3 && (scur + 1 < nslab)){
      if constexpr (NL == 25) asm volatile("s_waitcnt vmcnt(29)" ::: "memory");
      else if constexpr (NL == 17) asm volatile("s_waitcnt vmcnt(21)" ::: "memory");
      else asm volatile("s_waitcnt vmcnt(18)" ::: "memory");
    } else {
      asm volatile("s_waitcnt vmcnt(4)" ::: "memory");
    }
    __builtin_amdgcn_s_barrier();
    asm volatile("" ::: "memory");

    const f16* bW = &smW[bfi*4096];
    f16x8 w0h = *(const f16x8*)&bW[offW];
    f16x8 w1h = *(const f16x8*)&bW[offW + 512];
    f16x8 w0l = *(const f16x8*)&bW[2048 + offW];
    f16x8 w1l = *(const f16x8*)&bW[2048 + offW + 512];

    int t3v = (tcur >= 6) ? 2 : ((tcur >= 3) ? 1 : 0);
    int doff = (t3v - 1)*TWD + (tcur - 3*t3v) - 1;
    int ib = cbase;
    f16x8 p0h, p0l, p1h, p1l;
    #pragma unroll
    for (int j=0;j<8;j++){
      float v0 = smI[ib + csj[j] + sid0 + doff];
      float v1 = smI[ib + csj[j] + sid1 + doff];
      f16 h0 = (f16)v0; p0h[j] = h0; p0l[j] = (f16)(v0 - (float)h0);
      f16 h1 = (f16)v1; p1h[j] = h1; p1l[j] = (f16)(v1 - (float)h1);
    }
    acc[0][0] = __builtin_amdgcn_mfma_f32_16x16x32_f16(w0h, p0h, acc[0][0], 0,0,0);
    acc[0][1] = __builtin_amdgcn_mfma_f32_16x16x32_f16(w0h, p1h, acc[0][1], 0,0,0);
    acc[1][0] = __builtin_amdgcn_mfma_f32_16x16x32_f16(w1h, p0h, acc[1][0], 0,0,0);
    acc[1][1] = __builtin_amdgcn_mfma_f32_16x16x32_f16(w1h, p1h, acc[1][1], 0,0,0);
    acc[0][0] = __builtin_amdgcn_mfma_f32_16x16x32_f16(w0h, p0l, acc[0][0], 0,0,0);
    acc[0][1] = __builtin_amdgcn_mfma_f32_16x16x32_f16(w0h, p1l, acc[0][1], 0,0,0);
    acc[1][0] = __builtin_amdgcn_mfma_f32_16x16x32_f16(w1h, p0l, acc[1][0], 0,0,0);
    acc[1][1] = __builtin_amdgcn_mfma_f32_16x16x32_f16(w1h, p1l, acc[1][1], 0,0,0);
    acc[0][0] = __builtin_amdgcn_mfma_f32_16x16x32_f16(w0l, p0h, acc[0][0], 0,0,0);
    acc[0][1] = __builtin_amdgcn_mfma_f32_16x16x32_f16(w0l, p1h, acc[0][1], 0,0,0);
    acc[1][0] = __builtin_amdgcn_mfma_f32_16x16x32_f16(w1l, p0h, acc[1][0], 0,0,0);
    acc[1][1] = __builtin_amdgcn_mfma_f32_16x16x32_f16(w1l, p1h, acc[1][1], 0,0,0);

    __builtin_amdgcn_s_barrier();
    asm volatile("" ::: "memory");
    int k0 = (stp_s3 < nslab) ? (stp_t3*Cip + stp_s3*32) : 0;
    stage(bfi, k0);
    if (++stp_t3 == 9){ stp_t3 = 0; stp_s3++; }
    bfi = (bfi == 2) ? 0 : bfi + 1;
    if (++tcur == 9){ tcur = 0; scur++; }
  }

  #pragma unroll
  for (int ri=0;ri<2;ri++)
  #pragma unroll
  for (int fc=0;fc<2;fc++)
  #pragma unroll
  for (int r=0;r<4;r++){
    int co = bn + wr*32 + ri*16 + (lane>>4)*4 + r;
    int pm = bm + wc*32 + fc*16 + (lane&15);
    if (co < Co){
      float v = acc[ri][fc][r] + bv[ri][r];
      v = fmaxf(v, 0.f);
      int hw = pm & (HW-1);
      out[((size_t)b*Co + co)*HW + hw] = v;
    }
  }
}

// sum S partial slices + bias + relu -> NCHW
__global__ void k_creduce(const float* __restrict__ part, const float* __restrict__ bias,
                          float* __restrict__ out, int M, int Np, int msh, int cosh, int hwsh, int S){
  int i = blockIdx.x*256 + threadIdx.x;
  int Co = 1<<cosh;
  if (i >= M*Co) return;
  int co = i >> msh, m = i & (M-1);
  float v = bias[co];
  for (int s=0;s<S;s++) v += part[((size_t)s*M + m)*Np + co];
  v = fmaxf(v, 0.f);
  int HW = 1<<hwsh;
  int b = m >> hwsh, hw = m & (HW-1);
  out[((size_t)b*Co + co)*HW + hw] = v;
}

// ---------------- pipelined split-f16 MFMA GEMM (up-convs, scatter epilogue) ----------------
__global__ __launch_bounds__(256) void k_gemm_hl(
    const f16* __restrict__ Wh, const f16* __restrict__ Wl,
    const f16* __restrict__ Ph, const f16* __restrict__ Pl,
    const float* __restrict__ bias, float* __restrict__ out,
    int N, int Kp, int wsh, int hwsh, int Co)
{
  __shared__ __align__(16) f16 sm[3*4*2048];
  int bn = blockIdx.y*64;
  int bm = blockIdx.x*64;
  int t = threadIdx.x;
  int lane = t & 63, wv = t >> 6;
  int wr = wv >> 1, wc = wv & 1;

  float bv[2][4];
  {
    int cb = bn + wr*32 + (lane>>4)*4;
    #pragma unroll
    for (int ri=0;ri<2;ri++)
      #pragma unroll
      for (int r=0;r<4;r++){
        int co = cb + ri*16 + r;
        int idx = co>>2, lim = N>>2;
        if (idx >= lim) idx = lim-1;
        bv[ri][r] = bias[idx];
      }
  }
  asm volatile("s_waitcnt vmcnt(0)" ::: "memory");

  int rr = lane >> 2;
  int cg = (lane & 3) ^ ((lane >> 3) & 3);
  size_t gW = (size_t)(bn + wv*16 + rr)*Kp + cg*8;
  size_t gP = (size_t)(bm + wv*16 + rr)*Kp + cg*8;
  int lb = wv*512;

  int rA = lane & 15, c = lane >> 4;
  int RW = wr*32 + rA; int sW = (RW>>1)&3;
  int offW = RW*32 + 8*(c ^ sW);
  int RP = wc*32 + rA; int sP = (RP>>1)&3;
  int offP = RP*32 + 8*(c ^ sP);

  f32x4 zz = {0.f,0.f,0.f,0.f};
  f32x4 acc[2][2];
  acc[0][0]=zz; acc[0][1]=zz; acc[1][0]=zz; acc[1][1]=zz;

  auto stage = [&](int bfi, int kk){
    GLLDS(Wh + gW + kk, &sm[(bfi*4+0)*2048 + lb]);
    GLLDS(Wl + gW + kk, &sm[(bfi*4+1)*2048 + lb]);
    GLLDS(Ph + gP + kk, &sm[(bfi*4+2)*2048 + lb]);
    GLLDS(Pl + gP + kk, &sm[(bfi*4+3)*2048 + lb]);
  };

  int nt = Kp >> 5;
  stage(0, 0);
  stage(1, (nt>1)?32:0);
  stage(2, (nt>2)?64:0);

  for (int tt = 0; tt < nt; ++tt){
    asm volatile("s_waitcnt vmcnt(8)" ::: "memory");
    __builtin_amdgcn_s_barrier();
    asm volatile("" ::: "memory");
    int bfi = tt % 3;
    int base = bfi*8192;
    f16x8 w0h = *(const f16x8*)&sm[base + offW];
    f16x8 w1h = *(const f16x8*)&sm[base + offW + 512];
    f16x8 w0l = *(const f16x8*)&sm[base + 2048 + offW];
    f16x8 w1l = *(const f16x8*)&sm[base + 2048 + offW + 512];
    f16x8 p0h = *(const f16x8*)&sm[base + 4096 + offP];
    f16x8 p1h = *(const f16x8*)&sm[base + 4096 + offP + 512];
    f16x8 p0l = *(const f16x8*)&sm[base + 6144 + offP];
    f16x8 p1l = *(const f16x8*)&sm[base + 6144 + offP + 512];
    acc[0][0] = __builtin_amdgcn_mfma_f32_16x16x32_f16(w0h, p0h, acc[0][0], 0,0,0);
    acc[0][1] = __builtin_amdgcn_mfma_f32_16x16x32_f16(w0h, p1h, acc[0][1], 0,0,0);
    acc[1][0] = __builtin_amdgcn_mfma_f32_16x16x32_f16(w1h, p0h, acc[1][0], 0,0,0);
    acc[1][1] = __builtin_amdgcn_mfma_f32_16x16x32_f16(w1h, p1h, acc[1][1], 0,0,0);
    acc[0][0] = __builtin_amdgcn_mfma_f32_16x16x32_f16(w0h, p0l, acc[0][0], 0,0,0);
    acc[0][1] = __builtin_amdgcn_mfma_f32_16x16x32_f16(w0h, p1l, acc[0][1], 0,0,0);
    acc[1][0] = __builtin_amdgcn_mfma_f32_16x16x32_f16(w1h, p0l, acc[1][0], 0,0,0);
    acc[1][1] = __builtin_amdgcn_mfma_f32_16x16x32_f16(w1h, p1l, acc[1][1], 0,0,0);
    acc[0][0] = __builtin_amdgcn_mfma_f32_16x16x32_f16(w0l, p0h, acc[0][0], 0,0,0);
    acc[0][1] = __builtin_amdgcn_mfma_f32_16x16x32_f16(w0l, p1h, acc[0][1], 0,0,0);
    acc[1][0] = __builtin_amdgcn_mfma_f32_16x16x32_f16(w1l, p0h, acc[1][0], 0,0,0);
    acc[1][1] = __builtin_amdgcn_mfma_f32_16x16x32_f16(w1l, p1h, acc[1][1], 0,0,0);
    __builtin_amdgcn_s_barrier();
    asm volatile("" ::: "memory");
    int kn = (tt+3 < nt) ? (tt+3)*32 : 0;
    stage(bfi, kn);
  }

  int HW = 1<<hwsh;
  int Wi = 1<<wsh;
  int Hi = 1<<(hwsh-wsh);
  #pragma unroll
  for (int ri=0;ri<2;ri++)
  #pragma unroll
  for (int fc=0;fc<2;fc++)
  #pragma unroll
  for (int r=0;r<4;r++){
    int co = bn + wr*32 + ri*16 + (lane>>4)*4 + r;
    int m = bm + wc*32 + fc*16 + (lane&15);
    if (co < N){
      int o = co>>2, p=(co>>1)&1, q=co&1;
      float v = acc[ri][fc][r] + bv[ri][r];
      int bb = m >> hwsh;
      int ij = m & (HW-1);
      int i = ij >> wsh, j = ij & (Wi-1);
      out[(((size_t)bb*Co + o)*(2*Hi) + 2*i+p)*(2*Wi) + 2*j+q] = v;
    }
  }
}

// ---------------- split-K MFMA GEMM, fp32 W and P (in-register hi/lo) ----------------
__global__ __launch_bounds__(256) void k_gemm_w32s(
    const float* __restrict__ Wf, int ldaW,
    const float* __restrict__ Pf, int ldaP,
    float* __restrict__ out, int N, int KS, int Mreal, int ldc, int sliceStride)
{
  __shared__ __align__(16) float smW[3*2048];
  __shared__ __align__(16) float smP[3*2048];
  int bn = blockIdx.y*64;
  int bm = blockIdx.x*64;
  int kz = blockIdx.z*KS;
  int t = threadIdx.x;
  int lane = t & 63, wv = t >> 6;
  int wr = wv >> 1, wc = wv & 1;

  int wcs = (lane & 7) ^ (lane >> 3);
  size_t gWoff = (size_t)(bn + wv*16 + (lane>>3))*ldaW + wcs*4 + kz;
  size_t gPoff = (size_t)(bm + wv*16 + (lane>>3))*ldaP + wcs*4 + kz;

  int rA = lane & 15, c = lane >> 4;
  int RW0 = wr*32 + rA;  int swzW = RW0 & 7;
  int RP0 = wc*32 + rA;  int swzP = RP0 & 7;
  int cw0 = ((2*c)   ^ swzW)*4;
  int cw1 = ((2*c+1) ^ swzW)*4;
  int pc0 = ((2*c)   ^ swzP)*4;
  int pc1 = ((2*c+1) ^ swzP)*4;

  f32x4 zz = {0.f,0.f,0.f,0.f};
  f32x4 acc[2][2];
  acc[0][0]=zz; acc[0][1]=zz; acc[1][0]=zz; acc[1][1]=zz;

  auto stage = [&](int bfi, int kk){
    GLLDS(Wf + gWoff + kk,                  &smW[bfi*2048 + wv*512]);
    GLLDS(Wf + gWoff + kk + 8*(size_t)ldaW, &smW[bfi*2048 + wv*512 + 256]);
    GLLDS(Pf + gPoff + kk,                  &smP[bfi*2048 + wv*512]);
    GLLDS(Pf + gPoff + kk + 8*(size_t)ldaP, &smP[bfi*2048 + wv*512 + 256]);
  };

  int nt = KS >> 5;
  stage(0, 0);
  stage(1, (nt>1)?32:0);
  stage(2, (nt>2)?64:0);

  for (int tt = 0; tt < nt; ++tt){
    asm volatile("s_waitcnt vmcnt(8)" ::: "memory");
    __builtin_amdgcn_s_barrier();
    asm volatile("" ::: "memory");
    int bfi = tt % 3;
    const float* bW = &smW[bfi*2048];
    const float* bP = &smP[bfi*2048];
    f32x4 a0 = *(const f32x4*)&bW[RW0*32 + cw0];
    f32x4 a1 = *(const f32x4*)&bW[RW0*32 + cw1];
    f32x4 a2 = *(const f32x4*)&bW[RW0*32 + 512 + cw0];
    f32x4 a3 = *(const f32x4*)&bW[RW0*32 + 512 + cw1];
    f32x4 b0 = *(const f32x4*)&bP[RP0*32 + pc0];
    f32x4 b1 = *(const f32x4*)&bP[RP0*32 + pc1];
    f32x4 b2 = *(const f32x4*)&bP[RP0*32 + 512 + pc0];
    f32x4 b3 = *(const f32x4*)&bP[RP0*32 + 512 + pc1];
    f16x8 w0h, w0l, w1h, w1l, p0h, p0l, p1h, p1l;
    #pragma unroll
    for (int j=0;j<4;j++){
      f16 h;
      h=(f16)a0[j]; w0h[j]=h;   w0l[j]  =(f16)(a0[j]-(float)h);
      h=(f16)a1[j]; w0h[4+j]=h; w0l[4+j]=(f16)(a1[j]-(float)h);
      h=(f16)a2[j]; w1h[j]=h;   w1l[j]  =(f16)(a2[j]-(float)h);
      h=(f16)a3[j]; w1h[4+j]=h; w1l[4+j]=(f16)(a3[j]-(float)h);
      h=(f16)b0[j]; p0h[j]=h;   p0l[j]  =(f16)(b0[j]-(float)h);
      h=(f16)b1[j]; p0h[4+j]=h; p0l[4+j]=(f16)(b1[j]-(float)h);
      h=(f16)b2[j]; p1h[j]=h;   p1l[j]  =(f16)(b2[j]-(float)h);
      h=(f16)b3[j]; p1h[4+j]=h; p1l[4+j]=(f16)(b3[j]-(float)h);
    }
    acc[0][0] = __builtin_amdgcn_mfma_f32_16x16x32_f16(w0h, p0h, acc[0][0], 0,0,0);
    acc[0][1] = __builtin_amdgcn_mfma_f32_16x16x32_f16(w0h, p1h, acc[0][1], 0,0,0);
    acc[1][0] = __builtin_amdgcn_mfma_f32_16x16x32_f16(w1h, p0h, acc[1][0], 0,0,0);
    acc[1][1] = __builtin_amdgcn_mfma_f32_16x16x32_f16(w1h, p1h, acc[1][1], 0,0,0);
    acc[0][0] = __builtin_amdgcn_mfma_f32_16x16x32_f16(w0h, p0l, acc[0][0], 0,0,0);
    acc[0][1] = __builtin_amdgcn_mfma_f32_16x16x32_f16(w0h, p1l, acc[0][1], 0,0,0);
    acc[1][0] = __builtin_amdgcn_mfma_f32_16x16x32_f16(w1h, p0l, acc[1][0], 0,0,0);
    acc[1][1] = __builtin_amdgcn_mfma_f32_16x16x32_f16(w1h, p1l, acc[1][1], 0,0,0);
    acc[0][0] = __builtin_amdgcn_mfma_f32_16x16x32_f16(w0l, p0h, acc[0][0], 0,0,0);
    acc[0][1] = __builtin_amdgcn_mfma_f32_16x16x32_f16(w0l, p1h, acc[0][1], 0,0,0);
    acc[1][0] = __builtin_amdgcn_mfma_f32_16x16x32_f16(w1l, p0h, acc[1][0], 0,0,0);
    acc[1][1] = __builtin_amdgcn_mfma_f32_16x16x32_f16(w1l, p1h, acc[1][1], 0,0,0);
    __builtin_amdgcn_s_barrier();
    asm volatile("" ::: "memory");
    int kn = (tt+3 < nt) ? (tt+3)*32 : 0;
    stage(bfi, kn);
  }

  #pragma unroll
  for (int ri=0;ri<2;ri++)
  #pragma unroll
  for (int fc=0;fc<2;fc++)
  #pragma unroll
  for (int r=0;r<4;r++){
    int co = bn + wr*32 + ri*16 + (lane>>4)*4 + r;
    int m  = bm + wc*32 + fc*16 + (lane&15);
    if (m < Mreal)
      out[((size_t)blockIdx.z*sliceStride + m)*ldc + co] = acc[ri][fc][r];
  }
}

// ---------------- dt projection + slice-sum of xdbl ----------------
// Also writes xds[row*64+c] = sum_s xdp[s][row][c]  (block x==0 only)
__global__ __launch_bounds__(256) void k_dt(
    const float* __restrict__ xdp, const float* __restrict__ dtW,
    const float* __restrict__ dtB, float* __restrict__ dtb, float* __restrict__ xds)
{
  __shared__ float smP[64*68];
  __shared__ float smW[64*36];
  int bn = blockIdx.x*64;
  int bm = blockIdx.y*64;
  int t = threadIdx.x, lane = t&63, wv = t>>6, wr = wv>>1, wc = wv&1;
  {
    int row = t>>2, c0 = (t&3)*16;
    #pragma unroll
    for (int j=0;j<16;j++){
      int cc = c0+j;
      float pv = 0.f;
      #pragma unroll
      for (int s=0;s<4;s++) pv += xdp[((size_t)(s*192) + bm+row)*64 + cc];
      smP[row*68 + cc] = pv;
      if (blockIdx.x == 0) xds[(size_t)(bm+row)*64 + cc] = pv;
    }
    int cw0 = (t&3)*8;
    #pragma unroll
    for (int j=0;j<8;j++){
      int cc = cw0+j;
      smW[row*36 + cc] = dtW[(size_t)(bn+row)*32 + cc];
    }
  }
  __syncthreads();
  int rA = lane&15, c = lane>>4;
  int c8 = c*8;
  f32x4 a0 = *(const f32x4*)&smW[(wr*32+rA)*36 + c8];
  f32x4 a1 = *(const f32x4*)&smW[(wr*32+rA)*36 + c8+4];
  f32x4 a2 = *(const f32x4*)&smW[(wr*32+16+rA)*36 + c8];
  f32x4 a3 = *(const f32x4*)&smW[(wr*32+16+rA)*36 + c8+4];
  f32x4 b0 = *(const f32x4*)&smP[(wc*32+rA)*68 + c8];
  f32x4 b1 = *(const f32x4*)&smP[(wc*32+rA)*68 + c8+4];
  f32x4 b2 = *(const f32x4*)&smP[(wc*32+16+rA)*68 + c8];
  f32x4 b3 = *(const f32x4*)&smP[(wc*32+16+rA)*68 + c8+4];
  f16x8 w0h, w0l, w1h, w1l, p0h, p0l, p1h, p1l;
  #pragma unroll
  for (int j=0;j<4;j++){
    f16 h;
    h=(f16)a0[j]; w0h[j]=h;   w0l[j]  =(f16)(a0[j]-(float)h);
    h=(f16)a1[j]; w0h[4+j]=h; w0l[4+j]=(f16)(a1[j]-(float)h);
    h=(f16)a2[j]; w1h[j]=h;   w1l[j]  =(f16)(a2[j]-(float)h);
    h=(f16)a3[j]; w1h[4+j]=h; w1l[4+j]=(f16)(a3[j]-(float)h);
    h=(f16)b0[j]; p0h[j]=h;   p0l[j]  =(f16)(b0[j]-(float)h);
    h=(f16)b1[j]; p0h[4+j]=h; p0l[4+j]=(f16)(b1[j]-(float)h);
    h=(f16)b2[j]; p1h[j]=h;   p1l[j]  =(f16)(b2[j]-(float)h);
    h=(f16)b3[j]; p1h[4+j]=h; p1l[4+j]=(f16)(b3[j]-(float)h);
  }
  f32x4 zz = {0.f,0.f,0.f,0.f};
  f32x4 acc[2][2];
  acc[0][0]=zz; acc[0][1]=zz; acc[1][0]=zz; acc[1][1]=zz;
  acc[0][0] = __builtin_amdgcn_mfma_f32_16x16x32_f16(w0h, p0h, acc[0][0], 0,0,0);
  acc[0][1] = __builtin_amdgcn_mfma_f32_16x16x32_f16(w0h, p1h, acc[0][1], 0,0,0);
  acc[1][0] = __builtin_amdgcn_mfma_f32_16x16x32_f16(w1h, p0h, acc[1][0], 0,0,0);
  acc[1][1] = __builtin_amdgcn_mfma_f32_16x16x32_f16(w1h, p1h, acc[1][1], 0,0,0);
  acc[0][0] = __builtin_amdgcn_mfma_f32_16x16x32_f16(w0h, p0l, acc[0][0], 0,0,0);
  acc[0][1] = __builtin_amdgcn_mfma_f32_16x16x32_f16(w0h, p1l, acc[0][1], 0,0,0);
  acc[1][0] = __builtin_amdgcn_mfma_f32_16x16x32_f16(w1h, p0l, acc[1][0], 0,0,0);
  acc[1][1] = __builtin_amdgcn_mfma_f32_16x16x32_f16(w1h, p1l, acc[1][1], 0,0,0);
  acc[0][0] = __builtin_amdgcn_mfma_f32_16x16x32_f16(w0l, p0h, acc[0][0], 0,0,0);
  acc[0][1] = __builtin_amdgcn_mfma_f32_16x16x32_f16(w0l, p1h, acc[0][1], 0,0,0);
  acc[1][0] = __builtin_amdgcn_mfma_f32_16x16x32_f16(w1l, p0h, acc[1][0], 0,0,0);
  acc[1][1] = __builtin_amdgcn_mfma_f32_16x16x32_f16(w1l, p1h, acc[1][1], 0,0,0);
  #pragma unroll
  for (int ri=0;ri<2;ri++)
  #pragma unroll
  for (int fc=0;fc<2;fc++)
  #pragma unroll
  for (int r=0;r<4;r++){
    int co = bn + wr*32 + ri*16 + (lane>>4)*4 + r;
    int m  = bm + wc*32 + fc*16 + (lane&15);
    if (m < 130)
      dtb[(size_t)m*1024 + co] = softplusf(acc[ri][fc][r] + dtB[co]);
  }
}

__global__ void k_maxpool2(const float* __restrict__ in, float* __restrict__ out, int BC, int H, int W){
  int Ho=H/2, Wo=W/2;
  int idx = blockIdx.x*blockDim.x + threadIdx.x;
  if (idx >= BC*Ho*Wo) return;
  int xo = idx % Wo; int yo = (idx / Wo) % Ho; int c = idx / (Wo*Ho);
  const float* p = in + ((size_t)c*H + 2*yo)*W + 2*xo;
  out[idx] = fmaxf(fmaxf(p[0],p[1]), fmaxf(p[W],p[W+1]));
}

// ---------------- Mamba ----------------
__global__ void k_build_tok(const float* __restrict__ p4, const float* __restrict__ cls,
                            float* __restrict__ hidp, float* __restrict__ residual){
  int idx = blockIdx.x*blockDim.x+threadIdx.x;
  if (idx >= 2*65*512) return;
  int d = idx % 512; int l = (idx/512)%65; int b = idx/(512*65);
  float v = (l==0) ? cls[d] : p4[((size_t)b*512+d)*64 + (l-1)];
  int row = b*65 + l;
  residual[(size_t)row*512 + d] = v;
  hidp[(size_t)row*512 + d] = v;
  #pragma unroll
  for (int s=1;s<8;s++) hidp[((size_t)(s*192) + row)*512 + d] = 0.f;
}

__global__ void k_add_ln(float* __restrict__ residual, const float* __restrict__ hidp,
                         const float* __restrict__ nw, const float* __restrict__ nb,
                         float* __restrict__ hs){
  int row = blockIdx.x;
  int t = threadIdx.x;
  __shared__ float red[256];
  size_t base = (size_t)row*512;
  float h0 = 0.f, h1 = 0.f;
  #pragma unroll
  for (int s=0;s<8;s++){
    h0 += hidp[((size_t)(s*192) + row)*512 + t];
    h1 += hidp[((size_t)(s*192) + row)*512 + 256 + t];
  }
  float v0 = residual[base + t]       + h0;
  float v1 = residual[base + 256 + t] + h1;
  residual[base+t]=v0; residual[base+256+t]=v1;
  red[t]=v0+v1; __syncthreads();
  for(int o=128;o>0;o>>=1){ if(t<o) red[t]+=red[t+o]; __syncthreads(); }
  float mean = red[0]/512.f; __syncthreads();
  float d0=v0-mean, d1=v1-mean;
  red[t]=d0*d0+d1*d1; __syncthreads();
  for(int o=128;o>0;o>>=1){ if(t<o) red[t]+=red[t+o]; __syncthreads(); }
  float rstd = rsqrtf(red[0]/512.f + 1e-5f);
  hs[base+t]     = d0*rstd*nw[t]     + nb[t];
  hs[base+256+t] = d1*rstd*nw[256+t] + nb[256+t];
}

__global__ void k_conv1d_silu(const float* __restrict__ xzp, const float* __restrict__ cw,
                              const float* __restrict__ cb, float* __restrict__ xc){
  int d = blockIdx.x*blockDim.x + threadIdx.x;
  int l = blockIdx.y, b = blockIdx.z;
  if (d>=1024) return;
  float acc = cb[d];
  #pragma unroll
  for(int k=0;k<4;k++){
    int lp = l-3+k;
    if (lp>=0){
      size_t r = (size_t)(b*65+lp);
      float xzv = xzp[r*2048 + d] + xzp[(r + 192)*2048 + d];
      acc = fmaf(xzv, cw[d*4+k], acc);
    }
  }
  xc[((size_t)(b*65+l))*1024 + d] = siluf(acc);
}

__global__ void k_scan(const float* __restrict__ dt, const float* __restrict__ xc,
                       const float* __restrict__ xds, const float* __restrict__ xzp,
                       const float* __restrict__ Alog, const float* __restrict__ Dp,
                       float* __restrict__ gt){
  int gid = blockIdx.x*blockDim.x + threadIdx.x;
  if (gid >= 2*1024*16) return;
  int n = gid & 15;
  int d = (gid >> 4) & 1023;
  int b = gid >> 14;
  float A = -expf(Alog[d*16+n]);
  float Dv = Dp[d];
  float h = 0.f;
  for (int l=0;l<65;l++){
    size_t r = (size_t)(b*65+l);
    float dtv = dt[r*1024+d];
    float xcv = xc[r*1024+d];
    float Bn = xds[r*64 + 32 + n];
    float Cn = xds[r*64 + 48 + n];
    h = fmaf(expf(dtv*A), h, dtv*xcv*Bn);
    float y = h*Cn;
    y += __shfl_xor(y, 1); y += __shfl_xor(y, 2);
    y += __shfl_xor(y, 4); y += __shfl_xor(y, 8);
    if (n==0){
      float zv = xzp[r*2048 + 1024 + d] + xzp[(r + 192)*2048 + 1024 + d];
      gt[r*1024+d] = (y + Dv*xcv) * siluf(zv);
    }
  }
}

__global__ void k_xsp(const float* __restrict__ hidp, float* __restrict__ xsp){
  int idx = blockIdx.x*blockDim.x+threadIdx.x;
  if (idx>=2*512*64) return;
  int j = idx & 63; int c = (idx>>6)&511; int b = idx>>15;
  int row = b*65 + 1 + j;
  float v = 0.f;
  #pragma unroll
  for (int s=0;s<8;s++) v += hidp[((size_t)(s*192) + row)*512 + c];
  xsp[idx] = v;
}

__global__ void k_conv1x1(const float* __restrict__ in, const float* __restrict__ w,
                          const float* __restrict__ bias, float* __restrict__ out){
  int hw = blockIdx.x*blockDim.x+threadIdx.x; if (hw>=128*128) return;
  int o = blockIdx.y, b = blockIdx.z;
  float acc = bias[o];
  #pragma unroll
  for(int c=0;c<32;c++) acc = fmaf(in[((size_t)(b*32+c))*16384 + hw], w[o*32+c], acc);
  out[((size_t)(b*4+o))*16384 + hw] = acc;
}

__global__ void k_resize16(const float* __restrict__ in, float* __restrict__ out){
  size_t idx = (size_t)blockIdx.x*blockDim.x + threadIdx.x;
  if (idx >= (size_t)2*4*2048*2048) return;
  int x = idx & 2047; int y = (int)((idx>>11)&2047); int c = (int)(idx>>22);
  float sx = ((float)x+0.5f)*(1.f/16.f) - 0.5f;
  float sy = ((float)y+0.5f)*(1.f/16.f) - 0.5f;
  int x0 = (int)floorf(sx); float fx = sx-(float)x0;
  int y0 = (int)floorf(sy); float fy = sy-(float)y0;
  int x0c = max(x0,0), x1c = min(x0+1,127);
  int y0c = max(y0,0), y1c = min(y0+1,127);
  const float* p = in + (size_t)c*16384;
  float v00=p[y0c*128+x0c], v01=p[y0c*128+x1c], v10=p[y1c*128+x0c], v11=p[y1c*128+x1c];
  out[idx] = (1.f-fy)*((1.f-fx)*v00 + fx*v01) + fy*((1.f-fx)*v10 + fx*v11);
}

// ---------------- host ----------------
#define MAX_A_ELEMS 524288

extern "C" void kernel_launch(void* const* d_in, const int* in_sizes, int n_in,
                              void* d_out, int out_size, void* d_ws, size_t ws_size,
                              hipStream_t stream) {
  const float* x        = (const float*)d_in[0];
  const float* masks    = (const float*)d_in[1];
  const float* ew1[4] = {(const float*)d_in[2],(const float*)d_in[6],(const float*)d_in[10],(const float*)d_in[14]};
  const float* eb1[4] = {(const float*)d_in[3],(const float*)d_in[7],(const float*)d_in[11],(const float*)d_in[15]};
  const float* ew2[4] = {(const float*)d_in[4],(const float*)d_in[8],(const float*)d_in[12],(const float*)d_in[16]};
  const float* eb2[4] = {(const float*)d_in[5],(const float*)d_in[9],(const float*)d_in[13],(const float*)d_in[17]};
  const float* cls      = (const float*)d_in[18];
  const float* norm_w   = (const float*)d_in[19];
  const float* norm_b   = (const float*)d_in[20];
  const float* in_proj  = (const float*)d_in[21];
  const float* conv1d_w = (const float*)d_in[22];
  const float* conv1d_b = (const float*)d_in[23];
  const float* x_proj   = (const float*)d_in[24];
  const float* dt_w     = (const float*)d_in[25];
  const float* dt_b     = (const float*)d_in[26];
  const float* A_log    = (const float*)d_in[27];
  const float* D_ssm    = (const float*)d_in[28];
  const float* out_proj = (const float*)d_in[29];
  const float* dup_w[4] = {(const float*)d_in[30],(const float*)d_in[36],(const float*)d_in[42],(const float*)d_in[48]};
  const float* dup_b[4] = {(const float*)d_in[31],(const float*)d_in[37],(const float*)d_in[43],(const float*)d_in[49]};
  const float* dw1[4]   = {(const float*)d_in[32],(const float*)d_in[38],(const float*)d_in[44],(const float*)d_in[50]};
  const float* db1[4]   = {(const float*)d_in[33],(const float*)d_in[39],(const float*)d_in[45],(const float*)d_in[51]};
  const float* dw2[4]   = {(const float*)d_in[34],(const float*)d_in[40],(const float*)d_in[46],(const float*)d_in[52]};
  const float* db2[4]   = {(const float*)d_in[35],(const float*)d_in[41],(const float*)d_in[47],(const float*)d_in[53]};
  const float* final_w  = (const float*)d_in[54];
  const float* final_b  = (const float*)d_in[55];
  float* out = (float*)d_out;

  float* W = (float*)d_ws;
  size_t off = 0;
  auto alloc = [&](size_t n){ float* p = W + off; off += n; return p; };

  float* Tre = alloc(32768);  float* Tim = alloc(32768);
  float* Fre = alloc(32768);  float* Fim = alloc(32768);
  float* Gre = alloc(196608); float* Gim = alloc(196608);
  float* xfreq = alloc(98304);
  float* tmpA = alloc(2097152);
  float* e1 = alloc(2097152);
  float* p1 = alloc(524288);
  float* e2 = alloc(1048576);
  float* p2 = alloc(262144);
  float* e3 = alloc(524288);
  float* p3 = alloc(131072);
  float* e4 = alloc(262144);
  float* p4 = alloc(65536);
  float* residual = alloc(66560);
  float* xsp = alloc(65536);
  float* tmpB = alloc(1048576);
  float* d4 = alloc(131072);
  float* d3 = alloc(262144);
  float* d2 = alloc(524288);
  float* d1 = alloc(1048576);
  float* fin = alloc(131072);
  (void)ws_size; (void)n_in; (void)in_sizes; (void)out_size;

  // ---- weight descriptor table: conv_ig (e1a,e1b,e2a,e2b,d2a,d2b,d1a,d1b) + up x4 ----
  WAll wa;
  {
    const float* s[NWD] = { ew1[0], ew2[0], ew1[1], ew2[1],
                            dw1[2], dw2[2], dw1[3], dw2[3],
                            dup_w[0], dup_w[1], dup_w[2], dup_w[3] };
    const int N_[NWD]  = {64,64,128,128, 64,64,32,32, 1024,512,256,128};
    const int CI_[NWD] = {3,64,64,128, 192,64,96,32, 512,256,128,64};
    const int U_[NWD]  = {0,0,0,0, 0,0,0,0, 256,128,64,32};
    int cacc = 0;
    for (int i=0;i<NWD;i++){
      wa.src[i]=s[i]; wa.N[i]=N_[i]; wa.up[i]=U_[i]; wa.ci[i]=CI_[i];
      int cip = (CI_[i]+31)&~31;
      wa.cip[i] = cip;
      wa.Kp[i] = U_[i] ? CI_[i] : 9*cip;
      wa.cum[i]=cacc;
      int Np=(N_[i]+63)&~63;
      cacc += Np*wa.Kp[i];
    }
    wa.cum[NWD]=cacc;
  }
  int wtotal = wa.cum[NWD];

  // ---- scratch in d_out (all dead before k_resize16 rewrites it) ----
  f16* q = (f16*)d_out;
  f16* Ahi = q; q += MAX_A_ELEMS;
  f16* Alo = q; q += MAX_A_ELEMS;
  f16* Ball_h = q; q += wtotal;
  f16* Ball_l = q; q += wtotal;
  float* fb = (float*)q;
  size_t foff = 0;
  auto falloc = [&](size_t n){ float* p = fb + foff; foff += n; return p; };
  float* convpart = falloc(2097152);
  float* Af32 = falloc(7340032);
  float* xzp  = falloc(2*192*2048);
  float* xdp  = falloc(4*192*64);
  float* xds  = falloc(192*64);
  float* hidp = falloc(8*192*512);
  float* hs   = falloc(192*512);
  float* xc   = falloc(192*1024);
  float* gt   = falloc(192*1024);
  float* dtb  = falloc(192*1024);

  hipLaunchKernelGGL(k_wcvt_all, dim3((wtotal+255)/256), dim3(256), 0, stream, wa, wtotal, Ball_h, Ball_l);

  // ---- frequency band split ----
  hipLaunchKernelGGL(k_dft_rows, dim3(128,2), dim3(128), 0, stream, x, Tre, Tim);
  hipLaunchKernelGGL(k_dft_cols, dim3(128,2), dim3(128), 0, stream, Tre, Tim, Fre, Fim);
  hipLaunchKernelGGL(k_idft_cols, dim3(128,3,2), dim3(128), 0, stream, Fre, Fim, masks, Gre, Gim);
  hipLaunchKernelGGL(k_idft_rows, dim3(128,3,2), dim3(128), 0, stream, Gre, Gim, xfreq);

  auto ctz = [](int v){ int s=0; while(!(v&1)){v>>=1;s++;} return s; };
  auto conv_ig = [&](const float* i1,int C1,const float* i2,int C2,
                     int widx, const float* bias, float* o, int Co, int H){
    int Wd = H;
    int Ci = C1+C2, Cip = (Ci+31)&~31;
    int M = 2*H*Wd, Np = (Co+63)&~63;
    int wsh = ctz(Wd), hwsh = ctz(H*Wd);
    int civ = Ci < 32 ? Ci : 32;
    const f16* bh = Ball_h + wa.cum[widx];
    const f16* bl = Ball_l + wa.cum[widx];
    dim3 g(M/64, Np/64);
    if (Wd >= 64)
      hipLaunchKernelGGL((k_conv_ig<25>), g, dim3(256), 0, stream, i1,C1,i2,C2,bh,bl,bias,o,Co,H,Wd,wsh,hwsh,Cip,civ);
    else if (Wd == 32)
      hipLaunchKernelGGL((k_conv_ig<17>), g, dim3(256), 0, stream, i1,C1,i2,C2,bh,bl,bias,o,Co,H,Wd,wsh,hwsh,Cip,civ);
    else
      hipLaunchKernelGGL((k_conv_ig<14>), g, dim3(256), 0, stream, i1,C1,i2,C2,bh,bl,bias,o,Co,H,Wd,wsh,hwsh,Cip,civ);
  };
  auto conv_sk = [&](const float* i1,int C1,const float* i2,int C2,
                     const float* wraw, const float* bias, float* o, int Co, int H, int S){
    int Wd = H;
    int Ci = C1+C2, K = Ci*9;
    int M = 2*H*Wd;
    int wsh = ctz(Wd), hwsh = ctz(H*Wd);
    hipLaunchKernelGGL(k_im2col32, dim3((K+255)/256, M), dim3(256), 0, stream,
                       i1, C1, i2, C2, H, Wd, wsh, hwsh, K, Af32);
    int KS = K / S;
    hipLaunchKernelGGL(k_gemm_w32s, dim3(M/64, Co/64, S), dim3(256), 0, stream,
                       wraw, K, Af32, K, convpart, Co, KS, M, Co, M);
    hipLaunchKernelGGL(k_creduce, dim3((M*Co+255)/256), dim3(256), 0, stream,
                       convpart, bias, o, M, Co, ctz(M), ctz(Co), hwsh, S);
  };
  auto up_bf = [&](const float* in, int widx, const float* bias, float* o,
                   int Ci,int Co,int Hi){
    int Kp=Ci, N=4*Co;
    int M=2*Hi*Hi;
    int wsh=ctz(Hi), hwsh=ctz(Hi*Hi);
    const f16* bh = Ball_h + wa.cum[widx];
    const f16* bl = Ball_l + wa.cum[widx];
    hipLaunchKernelGGL(k_im2col, dim3((Kp+255)/256, M), dim3(256), 0, stream,
                       in, Ci, Hi, Hi, wsh, hwsh, Ci, Kp, Ahi, Alo);
    hipLaunchKernelGGL(k_gemm_hl, dim3(M/64, N/64), dim3(256), 0, stream,
                       bh, bl, Ahi, Alo, bias, o, N, Kp, wsh, hwsh, Co);
  };

  // ---- encoder ----
  conv_ig(xfreq,3,  nullptr,0, 0, eb1[0], tmpA, 64, 128);
  conv_ig(tmpA,64,  nullptr,0, 1, eb2[0], e1,   64, 128);
  hipLaunchKernelGGL(k_maxpool2, dim3((2*64*64*64+255)/256), dim3(256), 0, stream, e1, p1, 2*64, 128,128);
  conv_ig(p1,64,    nullptr,0, 2, eb1[1], tmpA, 128, 64);
  conv_ig(tmpA,128, nullptr,0, 3, eb2[1], e2,   128, 64);
  hipLaunchKernelGGL(k_maxpool2, dim3((2*128*32*32+255)/256), dim3(256), 0, stream, e2, p2, 2*128, 64,64);
  conv_sk(p2,128,   nullptr,0, ew1[2], eb1[2], tmpA, 256, 32, 4);
  conv_sk(tmpA,256, nullptr,0, ew2[2], eb2[2], e3,   256, 32, 4);
  hipLaunchKernelGGL(k_maxpool2, dim3((2*256*16*16+255)/256), dim3(256), 0, stream, e3, p3, 2*256, 32,32);
  conv_sk(p3,256,   nullptr,0, ew1[3], eb1[3], tmpA, 512, 16, 8);
  conv_sk(tmpA,512, nullptr,0, ew2[3], eb2[3], e4,   512, 16, 8);
  hipLaunchKernelGGL(k_maxpool2, dim3((2*512*8*8+255)/256), dim3(256), 0, stream, e4, p4, 2*512, 16,16);

  // ---- mamba stack ----
  hipLaunchKernelGGL(k_build_tok, dim3((2*65*512+255)/256), dim3(256), 0, stream, p4, cls, hidp, residual);
  for (int l=0;l<24;l++){
    const float* nw   = norm_w   + (size_t)l*512;
    const float* nb   = norm_b   + (size_t)l*512;
    const float* inW  = in_proj  + (size_t)l*2048*512;
    const float* cw   = conv1d_w + (size_t)l*1024*4;
    const float* cb   = conv1d_b + (size_t)l*1024;
    const float* xpW  = x_proj   + (size_t)l*64*1024;
    const float* dtW  = dt_w     + (size_t)l*1024*32;
    const float* dtB  = dt_b     + (size_t)l*1024;
    const float* Alg  = A_log    + (size_t)l*1024*16;
    const float* Dp   = D_ssm    + (size_t)l*1024;
    const float* outW = out_proj + (size_t)l*512*1024;

    hipLaunchKernelGGL(k_add_ln, dim3(130), dim3(256), 0, stream, residual, hidp, nw, nb, hs);
    hipLaunchKernelGGL(k_gemm_w32s, dim3(3,32,2), dim3(256), 0, stream,
                       inW, 512, hs, 512, xzp, 2048, 256, 130, 2048, 192);
    hipLaunchKernelGGL(k_conv1d_silu, dim3(4,65,2), dim3(256), 0, stream, xzp, cw, cb, xc);
    hipLaunchKernelGGL(k_gemm_w32s, dim3(3,1,4), dim3(256), 0, stream,
                       xpW, 1024, xc, 1024, xdp, 64, 256, 130, 64, 192);
    hipLaunchKernelGGL(k_dt, dim3(16,3), dim3(256), 0, stream, xdp, dtW, dtB, dtb, xds);
    hipLaunchKernelGGL(k_scan, dim3(128), dim3(256), 0, stream, dtb, xc, xds, xzp, Alg, Dp, gt);
    hipLaunchKernelGGL(k_gemm_w32s, dim3(3,8,8), dim3(256), 0, stream,
                       outW, 1024, gt, 1024, hidp, 512, 128, 130, 512, 192);
  }
  hipLaunchKernelGGL(k_xsp, dim3((2*512*64+255)/256), dim3(256), 0, stream, hidp, xsp);

  // ---- decoder ----
  up_bf(xsp, 8, dup_b[0], tmpB, 512, 256, 8);
  conv_sk(e4,512, tmpB,256, dw1[0], db1[0], tmpA, 256, 16, 8);
  conv_sk(tmpA,256, nullptr,0, dw2[0], db2[0], d4, 256, 16, 8);
  up_bf(d4, 9, dup_b[1], tmpB, 256, 128, 16);
  conv_sk(e3,256, tmpB,128, dw1[1], db1[1], tmpA, 128, 32, 4);
  conv_sk(tmpA,128, nullptr,0, dw2[1], db2[1], d3, 128, 32, 4);
  up_bf(d3, 10, dup_b[2], tmpB, 128, 64, 32);
  conv_ig(e2,128, tmpB,64, 4, db1[2], tmpA, 64, 64);
  conv_ig(tmpA,64, nullptr,0, 5, db2[2], d2, 64, 64);
  up_bf(d2, 11, dup_b[3], tmpB, 64, 32, 64);
  conv_ig(e1,64, tmpB,32, 6, db1[3], tmpA, 32, 128);
  conv_ig(tmpA,32, nullptr,0, 7, db2[3], d1, 32, 128);

  // ---- head ----
  hipLaunchKernelGGL(k_conv1x1, dim3((16384+255)/256, 4, 2), dim3(256), 0, stream, d1, final_w, final_b, fin);
  hipLaunchKernelGGL(k_resize16, dim3((size_t)(2*4*2048*2048)/256), dim3(256), 0, stream, fin, out);
}

// Round 14
// 3120.474 us; speedup vs baseline: 1.0473x; 1.0473x over previous
//
#include <hip/hip_runtime.h>
#include <math.h>

#define PI_F 3.14159265358979323846f
typedef _Float16 f16;
typedef __attribute__((ext_vector_type(8))) _Float16 f16x8;
typedef __attribute__((ext_vector_type(4))) float f32x4;

__device__ __forceinline__ float siluf(float x){ return x / (1.f + expf(-x)); }
__device__ __forceinline__ float softplusf(float x){ return fmaxf(x,0.f) + log1pf(expf(-fabsf(x))); }
__device__ __forceinline__ void f2hl(float v, f16& hi, f16& lo){
  hi = (f16)v;
  lo = (f16)(v - (float)hi);
}

// ---------------- DFT band filtering ----------------
__global__ void k_dft_rows(const float* __restrict__ x, float* __restrict__ Tre, float* __restrict__ Tim){
  int v = threadIdx.x; int y = blockIdx.x; int b = blockIdx.y;
  __shared__ float cs[128], sn[128];
  float ang = -2.f*PI_F*(float)v/128.f;
  cs[v]=cosf(ang); sn[v]=sinf(ang);
  __syncthreads();
  const float* row = x + (b*128+y)*128;
  float re=0.f, im=0.f;
  for(int n=0;n<128;n++){ float xv=row[n]; int ph=(v*n)&127; re=fmaf(xv,cs[ph],re); im=fmaf(xv,sn[ph],im); }
  int o=(b*128+y)*128+v; Tre[o]=re; Tim[o]=im;
}
__global__ void k_dft_cols(const float* __restrict__ Tre, const float* __restrict__ Tim,
                           float* __restrict__ Fre, float* __restrict__ Fim){
  int v=threadIdx.x; int u=blockIdx.x; int b=blockIdx.y;
  __shared__ float cs[128], sn[128];
  float ang=-2.f*PI_F*(float)v/128.f; cs[v]=cosf(ang); sn[v]=sinf(ang);
  __syncthreads();
  float re=0.f,im=0.f;
  for(int y=0;y<128;y++){
    int ph=(u*y)&127; float c=cs[ph], s=sn[ph];
    int o=(b*128+y)*128+v;
    float tr=Tre[o], ti=Tim[o];
    re += tr*c - ti*s; im += tr*s + ti*c;
  }
  int o=(b*128+u)*128+v; Fre[o]=re; Fim[o]=im;
}
__global__ void k_idft_cols(const float* __restrict__ Fre,const float* __restrict__ Fim,
                            const float* __restrict__ mask, float* __restrict__ Gre,float* __restrict__ Gim){
  int v=threadIdx.x; int y=blockIdx.x; int m=blockIdx.y; int b=blockIdx.z;
  __shared__ float cs[128], sn[128];
  float ang=-2.f*PI_F*(float)v/128.f; cs[v]=cosf(ang); sn[v]=sinf(ang);
  __syncthreads();
  float re=0.f,im=0.f;
  for(int u=0;u<128;u++){
    int ph=(u*y)&127; float c=cs[ph], s=sn[ph];
    float w = mask[(m*128+u)*128+v];
    int o=(b*128+u)*128+v;
    float fr=Fre[o]*w, fi=Fim[o]*w;
    re += fr*c + fi*s;
    im += fi*c - fr*s;
  }
  int o=((b*3+m)*128+y)*128+v;
  Gre[o]=re*(1.f/128.f); Gim[o]=im*(1.f/128.f);
}
__global__ void k_idft_rows(const float* __restrict__ Gre,const float* __restrict__ Gim, float* __restrict__ xf){
  int xc=threadIdx.x; int y=blockIdx.x; int m=blockIdx.y; int b=blockIdx.z;
  __shared__ float cs[128], sn[128];
  float ang=-2.f*PI_F*(float)xc/128.f; cs[xc]=cosf(ang); sn[xc]=sinf(ang);
  __syncthreads();
  float re=0.f;
  const float* gr=Gre+((b*3+m)*128+y)*128;
  const float* gi=Gim+((b*3+m)*128+y)*128;
  for(int v=0;v<128;v++){
    int ph=(v*xc)&127;
    re += gr[v]*cs[ph] + gi[v]*sn[ph];
  }
  xf[((b*3+m)*128+y)*128+xc] = re*(1.f/128.f);
}

// ---------------- batched weight conversion ----------------
#define NWD 20
struct WAll {
  const float* src[NWD];
  int N[NWD], Kp[NWD], up[NWD], ci[NWD], cip[NWD];
  int cum[NWD+1];
};
__global__ void k_wcvt_all(WAll d, int total, f16* __restrict__ bh, f16* __restrict__ bl){
  int gid = blockIdx.x*256 + threadIdx.x;
  if (gid >= total) return;
  int li = gid; const float* src = d.src[0];
  int N=d.N[0], Kp=d.Kp[0], up=d.up[0], Ci=d.ci[0], cip=d.cip[0];
  #pragma unroll
  for (int j=1;j<NWD;j++){
    if (gid >= d.cum[j]){
      li = gid - d.cum[j]; src=d.src[j]; N=d.N[j];Kp=d.Kp[j];up=d.up[j];Ci=d.ci[j];cip=d.cip[j];
    }
  }
  int n = li / Kp, k = li - n*Kp;
  float v = 0.f;
  if (up){
    int o = n>>2, p=(n>>1)&1, q=n&1;
    if (k < Ci) v = src[(((size_t)k*up + o)*2 + p)*2 + q];
  } else {
    int tap = k / cip, cc = k - tap*cip;
    if (n < N && cc < Ci) v = src[((size_t)n*Ci + cc)*9 + tap];
  }
  f16 h,l; f2hl(v,h,l);
  bh[gid]=h; bl[gid]=l;
}

// im2col for up-convs (f16 hi/lo): rows of M=B*H*W, k=ci
__global__ void k_im2col(const float* __restrict__ in1, int C1,
                         int H, int W, int wsh, int hwsh, int K, int Kp,
                         f16* __restrict__ Ah, f16* __restrict__ Al){
  int k = blockIdx.x*256 + threadIdx.x;
  int lm = blockIdx.y;
  if (k >= Kp) return;
  float val = 0.f;
  if (k < K){
    int m = lm;
    int b = m >> hwsh;
    int hw = m & ((1<<hwsh)-1);
    int y = hw >> wsh;
    int x = hw & (W-1);
    val = in1[(((size_t)b*C1 + k)*H + y)*W + x];
  }
  f16 h,l; f2hl(val,h,l);
  Ah[(size_t)lm*Kp + k] = h; Al[(size_t)lm*Kp + k] = l;
}

// im2col fp32 (3x3, pad 1), concat-aware: A[m*K + k], k = ci*9 + (ky*3+kx)
__global__ void k_im2col32(const float* __restrict__ in1, int C1,
                           const float* __restrict__ in2, int C2,
                           int H, int W, int wsh, int hwsh, int K,
                           float* __restrict__ A){
  int k = blockIdx.x*256 + threadIdx.x;
  int m = blockIdx.y;
  if (k >= K) return;
  int ci = k/9; int tt = k - ci*9;
  int dy = tt/3 - 1, dx = tt - (tt/3)*3 - 1;
  int b = m >> hwsh;
  int hw = m & ((1<<hwsh)-1);
  int y = (hw >> wsh) + dy;
  int x = (hw & (W-1)) + dx;
  float val = 0.f;
  if (y >= 0 && y < H && x >= 0 && x < W){
    val = (ci < C1) ? in1[(((size_t)b*C1 + ci)*H + y)*W + x]
                    : in2[(((size_t)b*C2 + (ci-C1))*H + y)*W + x];
  }
  A[(size_t)m*K + k] = val;
}

#define GLLDS(gp, ls) __builtin_amdgcn_global_load_lds( \
    (const __attribute__((address_space(1))) void*)(gp), \
    (__attribute__((address_space(3))) void*)(ls), 16, 0, 0)

// ---------------- implicit-GEMM conv3x3 (S=1 only; proven path for H>=64) ----------------
template<int NL>
__global__ __launch_bounds__(256) void k_conv_ig(
    const float* __restrict__ in1, int C1, const float* __restrict__ in2, int C2,
    const f16* __restrict__ Wh, const f16* __restrict__ Wl,
    const float* __restrict__ bias, float* __restrict__ out,
    int Co, int H, int W, int wsh, int hwsh, int Cip, int civ)
{
  __shared__ __align__(16) float smI[2*6464];
  __shared__ __align__(16) f16 smW[3*2*2048];
  const int HW = 1<<hwsh;
  const int tw = (W<64)?W:64;
  const int twsh = (wsh<6)?wsh:6;
  const int R = 64>>twsh;
  const int RT = R+2, TWD = tw+2;
  const int nspat = RT*TWD;
  const int CS = ((nspat+3)&~3)+2;
  const int total = nspat*32;
  const int nslab = Cip>>5;
  const int nsteps = 9*nslab;
  const int Kp = 9*Cip;

  int bn = blockIdx.y*64;
  int bm = blockIdx.x*64;
  int t = threadIdx.x;
  int lane = t&63, wv = t>>6;
  int wr = wv>>1, wc = wv&1;

  int b  = bm >> hwsh;
  int hw0 = bm & (HW-1);
  int y0 = hw0 >> wsh;
  int x0 = hw0 & (W-1);

  float bv[2][4];
  {
    int cb = bn + wr*32 + (lane>>4)*4;
    #pragma unroll
    for (int ri=0;ri<2;ri++)
      #pragma unroll
      for (int r=0;r<4;r++){
        int co = cb + ri*16 + r;
        bv[ri][r] = bias[co < Co ? co : Co-1];
      }
    asm volatile("s_waitcnt vmcnt(0)" ::: "memory");
  }

  int goff[NL], loff[NL];
  {
    int ci = 0, s = t;
    if (s >= nspat){ s -= nspat; ci++; }
    if (s >= nspat){ s -= nspat; ci++; }
    #pragma unroll
    for (int j=0;j<NL;j++){
      int rr_=0, sx=s;
      #pragma unroll
      for (int q=0;q<5;q++){ if (sx>=TWD){ sx-=TWD; rr_++; } }
      int gy = y0 - 1 + rr_;
      int gx = x0 - 1 + sx;
      int idx = t + j*256;
      bool intile = (idx < total);
      bool ok = intile && (ci < civ) && (gy>=0) && (gy<H) && (gx>=0) && (gx<W);
      goff[j] = ok ? (ci*HW + gy*W + gx) : -1;
      loff[j] = intile ? (ci*CS + rr_*TWD + sx) : -1;
      s += 256;
      if (s >= nspat){ s -= nspat; ci++; }
      if (s >= nspat){ s -= nspat; ci++; }
      if (s >= nspat){ s -= nspat; ci++; }
    }
  }

  int rr = lane >> 2;
  int cg = (lane & 3) ^ ((lane >> 3) & 3);
  size_t gW = (size_t)(bn + wv*16 + rr)*Kp + cg*8;
  int lb = wv*512;
  auto stage = [&](int bfi, int k0){
    GLLDS(Wh + gW + k0, &smW[(bfi*2+0)*2048 + lb]);
    GLLDS(Wl + gW + k0, &smW[(bfi*2+1)*2048 + lb]);
  };

  int rA = lane & 15, c = lane >> 4;
  int RW = wr*32 + rA; int sW = (RW>>1)&3;
  int offW = RW*32 + 8*(c ^ sW);
  int lp0 = wc*32 + rA, lp1 = lp0 + 16;
  int sid0 = ((lp0>>twsh)+1)*TWD + (lp0 & (tw-1)) + 1;
  int sid1 = ((lp1>>twsh)+1)*TWD + (lp1 & (tw-1)) + 1;
  int cbase = c*8*CS;
  int csj[8];
  #pragma unroll
  for (int j=0;j<8;j++) csj[j] = j*CS;

  auto srcptr = [&](int sl) -> const float* {
    int cbeg = sl*32;
    return (cbeg < C1) ? in1 + ((size_t)(b*C1 + cbeg))*HW
                       : in2 + ((size_t)(b*C2 + (cbeg - C1)))*HW;
  };

  float rin[NL];
  {
    const float* sp = srcptr(0);
    #pragma unroll
    for (int j=0;j<NL;j++) rin[j] = sp[goff[j] < 0 ? 0 : goff[j]];
  }
  stage(0, 0);
  stage(1, Cip);
  stage(2, 2*Cip);
  asm volatile("s_waitcnt vmcnt(6)" ::: "memory");
  #pragma unroll
  for (int j=0;j<NL;j++) if (loff[j] >= 0) smI[loff[j]] = (goff[j] < 0) ? 0.f : rin[j];
  asm volatile("s_waitcnt lgkmcnt(0)" ::: "memory");
  __builtin_amdgcn_s_barrier();
  asm volatile("" ::: "memory");
  if (nslab > 1){
    const float* sp = srcptr(1);
    #pragma unroll
    for (int j=0;j<NL;j++) rin[j] = sp[goff[j] < 0 ? 0 : goff[j]];
  }

  f32x4 zz = {0.f,0.f,0.f,0.f};
  f32x4 acc[2][2];
  acc[0][0]=zz; acc[0][1]=zz; acc[1][0]=zz; acc[1][1]=zz;

  int tcur = 0, scur = 0;
  int stp_t3 = 3, stp_s3 = 0;
  int bfi = 0;

  for (int step = 0; step < nsteps; ++step){
    if (tcur == 0 && step > 0){
      asm volatile("s_waitcnt vmcnt(6)" ::: "memory");
      int wb = (scur & 1)*6464;
      #pragma unroll
      for (int j=0;j<NL;j++) if (loff[j] >= 0) smI[wb + loff[j]] = (goff[j] < 0) ? 0.f : rin[j];
      asm volatile("s_waitcnt lgkmcnt(0)" ::: "memory");
      __builtin_amdgcn_s_barrier();
      asm volatile("" ::: "memory");
      if (scur + 1 < nslab){
        const float* sp = srcptr(scur+1);
        #pragma unroll
        for (int j=0;j<NL;j++) rin[j] = sp[goff[j] < 0 ? 0 : goff[j]];
      }
    }
    if (tcur < 3 && (scur + 1 < nslab)){
      if constexpr (NL == 25) asm volatile("s_waitcnt vmcnt(29)" ::: "memory");
      else if constexpr (NL == 17) asm volatile("s_waitcnt vmcnt(21)" ::: "memory");
      else asm volatile("s_waitcnt vmcnt(18)" ::: "memory");
    } else {
      asm volatile("s_waitcnt vmcnt(4)" ::: "memory");
    }
    __builtin_amdgcn_s_barrier();
    asm volatile("" ::: "memory");

    const f16* bW = &smW[bfi*4096];
    f16x8 w0h = *(const f16x8*)&bW[offW];
    f16x8 w1h = *(const f16x8*)&bW[offW + 512];
    f16x8 w0l = *(const f16x8*)&bW[2048 + offW];
    f16x8 w1l = *(const f16x8*)&bW[2048 + offW + 512];

    int t3v = (tcur >= 6) ? 2 : ((tcur >= 3) ? 1 : 0);
    int doff = (t3v - 1)*TWD + (tcur - 3*t3v) - 1;
    int ib = (scur & 1)*6464 + cbase;
    f16x8 p0h, p0l, p1h, p1l;
    #pragma unroll
    for (int j=0;j<8;j++){
      float v0 = smI[ib + csj[j] + sid0 + doff];
      float v1 = smI[ib + csj[j] + sid1 + doff];
      f16 h0 = (f16)v0; p0h[j] = h0; p0l[j] = (f16)(v0 - (float)h0);
      f16 h1 = (f16)v1; p1h[j] = h1; p1l[j] = (f16)(v1 - (float)h1);
    }
    acc[0][0] = __builtin_amdgcn_mfma_f32_16x16x32_f16(w0h, p0h, acc[0][0], 0,0,0);
    acc[0][1] = __builtin_amdgcn_mfma_f32_16x16x32_f16(w0h, p1h, acc[0][1], 0,0,0);
    acc[1][0] = __builtin_amdgcn_mfma_f32_16x16x32_f16(w1h, p0h, acc[1][0], 0,0,0);
    acc[1][1] = __builtin_amdgcn_mfma_f32_16x16x32_f16(w1h, p1h, acc[1][1], 0,0,0);
    acc[0][0] = __builtin_amdgcn_mfma_f32_16x16x32_f16(w0h, p0l, acc[0][0], 0,0,0);
    acc[0][1] = __builtin_amdgcn_mfma_f32_16x16x32_f16(w0h, p1l, acc[0][1], 0,0,0);
    acc[1][0] = __builtin_amdgcn_mfma_f32_16x16x32_f16(w1h, p0l, acc[1][0], 0,0,0);
    acc[1][1] = __builtin_amdgcn_mfma_f32_16x16x32_f16(w1h, p1l, acc[1][1], 0,0,0);
    acc[0][0] = __builtin_amdgcn_mfma_f32_16x16x32_f16(w0l, p0h, acc[0][0], 0,0,0);
    acc[0][1] = __builtin_amdgcn_mfma_f32_16x16x32_f16(w0l, p1h, acc[0][1], 0,0,0);
    acc[1][0] = __builtin_amdgcn_mfma_f32_16x16x32_f16(w1l, p0h, acc[1][0], 0,0,0);
    acc[1][1] = __builtin_amdgcn_mfma_f32_16x16x32_f16(w1l, p1h, acc[1][1], 0,0,0);

    __builtin_amdgcn_s_barrier();
    asm volatile("" ::: "memory");
    int k0 = (stp_s3 < nslab) ? (stp_t3*Cip + stp_s3*32) : 0;
    stage(bfi, k0);
    if (++stp_t3 == 9){ stp_t3 = 0; stp_s3++; }
    bfi = (bfi == 2) ? 0 : bfi + 1;
    if (++tcur == 9){ tcur = 0; scur++; }
  }

  #pragma unroll
  for (int ri=0;ri<2;ri++)
  #pragma unroll
  for (int fc=0;fc<2;fc++)
  #pragma unroll
  for (int r=0;r<4;r++){
    int co = bn + wr*32 + ri*16 + (lane>>4)*4 + r;
    int pm = bm + wc*32 + fc*16 + (lane&15);
    if (co < Co){
      float v = acc[ri][fc][r] + bv[ri][r];
      v = fmaxf(v, 0.f);
      int hw = pm & (HW-1);
      out[((size_t)b*Co + co)*HW + hw] = v;
    }
  }
}

// sum S partial slices + bias + relu -> NCHW
__global__ void k_creduce(const float* __restrict__ part, const float* __restrict__ bias,
                          float* __restrict__ out, int M, int Np, int msh, int cosh, int hwsh, int S){
  int i = blockIdx.x*256 + threadIdx.x;
  int Co = 1<<cosh;
  if (i >= M*Co) return;
  int co = i >> msh, m = i & (M-1);
  float v = bias[co];
  for (int s=0;s<S;s++) v += part[((size_t)s*M + m)*Np + co];
  v = fmaxf(v, 0.f);
  int HW = 1<<hwsh;
  int b = m >> hwsh, hw = m & (HW-1);
  out[((size_t)b*Co + co)*HW + hw] = v;
}

// ---------------- pipelined split-f16 MFMA GEMM (up-convs, scatter epilogue) ----------------
__global__ __launch_bounds__(256) void k_gemm_hl(
    const f16* __restrict__ Wh, const f16* __restrict__ Wl,
    const f16* __restrict__ Ph, const f16* __restrict__ Pl,
    const float* __restrict__ bias, float* __restrict__ out,
    int N, int Kp, int wsh, int hwsh, int Co)
{
  __shared__ __align__(16) f16 sm[3*4*2048];
  int bn = blockIdx.y*64;
  int bm = blockIdx.x*64;
  int t = threadIdx.x;
  int lane = t & 63, wv = t >> 6;
  int wr = wv >> 1, wc = wv & 1;

  float bv[2][4];
  {
    int cb = bn + wr*32 + (lane>>4)*4;
    #pragma unroll
    for (int ri=0;ri<2;ri++)
      #pragma unroll
      for (int r=0;r<4;r++){
        int co = cb + ri*16 + r;
        int idx = co>>2, lim = N>>2;
        if (idx >= lim) idx = lim-1;
        bv[ri][r] = bias[idx];
      }
  }
  asm volatile("s_waitcnt vmcnt(0)" ::: "memory");

  int rr = lane >> 2;
  int cg = (lane & 3) ^ ((lane >> 3) & 3);
  size_t gW = (size_t)(bn + wv*16 + rr)*Kp + cg*8;
  size_t gP = (size_t)(bm + wv*16 + rr)*Kp + cg*8;
  int lb = wv*512;

  int rA = lane & 15, c = lane >> 4;
  int RW = wr*32 + rA; int sW = (RW>>1)&3;
  int offW = RW*32 + 8*(c ^ sW);
  int RP = wc*32 + rA; int sP = (RP>>1)&3;
  int offP = RP*32 + 8*(c ^ sP);

  f32x4 zz = {0.f,0.f,0.f,0.f};
  f32x4 acc[2][2];
  acc[0][0]=zz; acc[0][1]=zz; acc[1][0]=zz; acc[1][1]=zz;

  auto stage = [&](int bfi, int kk){
    GLLDS(Wh + gW + kk, &sm[(bfi*4+0)*2048 + lb]);
    GLLDS(Wl + gW + kk, &sm[(bfi*4+1)*2048 + lb]);
    GLLDS(Ph + gP + kk, &sm[(bfi*4+2)*2048 + lb]);
    GLLDS(Pl + gP + kk, &sm[(bfi*4+3)*2048 + lb]);
  };

  int nt = Kp >> 5;
  stage(0, 0);
  stage(1, (nt>1)?32:0);
  stage(2, (nt>2)?64:0);

  for (int tt = 0; tt < nt; ++tt){
    asm volatile("s_waitcnt vmcnt(8)" ::: "memory");
    __builtin_amdgcn_s_barrier();
    asm volatile("" ::: "memory");
    int bfi = tt % 3;
    int base = bfi*8192;
    f16x8 w0h = *(const f16x8*)&sm[base + offW];
    f16x8 w1h = *(const f16x8*)&sm[base + offW + 512];
    f16x8 w0l = *(const f16x8*)&sm[base + 2048 + offW];
    f16x8 w1l = *(const f16x8*)&sm[base + 2048 + offW + 512];
    f16x8 p0h = *(const f16x8*)&sm[base + 4096 + offP];
    f16x8 p1h = *(const f16x8*)&sm[base + 4096 + offP + 512];
    f16x8 p0l = *(const f16x8*)&sm[base + 6144 + offP];
    f16x8 p1l = *(const f16x8*)&sm[base + 6144 + offP + 512];
    acc[0][0] = __builtin_amdgcn_mfma_f32_16x16x32_f16(w0h, p0h, acc[0][0], 0,0,0);
    acc[0][1] = __builtin_amdgcn_mfma_f32_16x16x32_f16(w0h, p1h, acc[0][1], 0,0,0);
    acc[1][0] = __builtin_amdgcn_mfma_f32_16x16x32_f16(w1h, p0h, acc[1][0], 0,0,0);
    acc[1][1] = __builtin_amdgcn_mfma_f32_16x16x32_f16(w1h, p1h, acc[1][1], 0,0,0);
    acc[0][0] = __builtin_amdgcn_mfma_f32_16x16x32_f16(w0h, p0l, acc[0][0], 0,0,0);
    acc[0][1] = __builtin_amdgcn_mfma_f32_16x16x32_f16(w0h, p1l, acc[0][1], 0,0,0);
    acc[1][0] = __builtin_amdgcn_mfma_f32_16x16x32_f16(w1h, p0l, acc[1][0], 0,0,0);
    acc[1][1] = __builtin_amdgcn_mfma_f32_16x16x32_f16(w1h, p1l, acc[1][1], 0,0,0);
    acc[0][0] = __builtin_amdgcn_mfma_f32_16x16x32_f16(w0l, p0h, acc[0][0], 0,0,0);
    acc[0][1] = __builtin_amdgcn_mfma_f32_16x16x32_f16(w0l, p1h, acc[0][1], 0,0,0);
    acc[1][0] = __builtin_amdgcn_mfma_f32_16x16x32_f16(w1l, p0h, acc[1][0], 0,0,0);
    acc[1][1] = __builtin_amdgcn_mfma_f32_16x16x32_f16(w1l, p1h, acc[1][1], 0,0,0);
    __builtin_amdgcn_s_barrier();
    asm volatile("" ::: "memory");
    int kn = (tt+3 < nt) ? (tt+3)*32 : 0;
    stage(bfi, kn);
  }

  int HW = 1<<hwsh;
  int Wi = 1<<wsh;
  int Hi = 1<<(hwsh-wsh);
  #pragma unroll
  for (int ri=0;ri<2;ri++)
  #pragma unroll
  for (int fc=0;fc<2;fc++)
  #pragma unroll
  for (int r=0;r<4;r++){
    int co = bn + wr*32 + ri*16 + (lane>>4)*4 + r;
    int m = bm + wc*32 + fc*16 + (lane&15);
    if (co < N){
      int o = co>>2, p=(co>>1)&1, q=co&1;
      float v = acc[ri][fc][r] + bv[ri][r];
      int bb = m >> hwsh;
      int ij = m & (HW-1);
      int i = ij >> wsh, j = ij & (Wi-1);
      out[(((size_t)bb*Co + o)*(2*Hi) + 2*i+p)*(2*Wi) + 2*j+q] = v;
    }
  }
}

// ---------------- split-K MFMA GEMM, fp32 W and P (in-register hi/lo) ----------------
// slice z handles k in [z*KS, (z+1)*KS); writes fp32 to out[(z*sliceStride+m)*ldc + co], m < Mreal.
__global__ __launch_bounds__(256) void k_gemm_w32s(
    const float* __restrict__ Wf, int ldaW,
    const float* __restrict__ Pf, int ldaP,
    float* __restrict__ out, int N, int KS, int Mreal, int ldc, int sliceStride)
{
  __shared__ __align__(16) float smW[3*2048];
  __shared__ __align__(16) float smP[3*2048];
  int bn = blockIdx.y*64;
  int bm = blockIdx.x*64;
  int kz = blockIdx.z*KS;
  int t = threadIdx.x;
  int lane = t & 63, wv = t >> 6;
  int wr = wv >> 1, wc = wv & 1;

  int wcs = (lane & 7) ^ (lane >> 3);
  size_t gWoff = (size_t)(bn + wv*16 + (lane>>3))*ldaW + wcs*4 + kz;
  size_t gPoff = (size_t)(bm + wv*16 + (lane>>3))*ldaP + wcs*4 + kz;

  int rA = lane & 15, c = lane >> 4;
  int RW0 = wr*32 + rA;  int swzW = RW0 & 7;
  int RP0 = wc*32 + rA;  int swzP = RP0 & 7;
  int cw0 = ((2*c)   ^ swzW)*4;
  int cw1 = ((2*c+1) ^ swzW)*4;
  int pc0 = ((2*c)   ^ swzP)*4;
  int pc1 = ((2*c+1) ^ swzP)*4;

  f32x4 zz = {0.f,0.f,0.f,0.f};
  f32x4 acc[2][2];
  acc[0][0]=zz; acc[0][1]=zz; acc[1][0]=zz; acc[1][1]=zz;

  auto stage = [&](int bfi, int kk){
    GLLDS(Wf + gWoff + kk,                  &smW[bfi*2048 + wv*512]);
    GLLDS(Wf + gWoff + kk + 8*(size_t)ldaW, &smW[bfi*2048 + wv*512 + 256]);
    GLLDS(Pf + gPoff + kk,                  &smP[bfi*2048 + wv*512]);
    GLLDS(Pf + gPoff + kk + 8*(size_t)ldaP, &smP[bfi*2048 + wv*512 + 256]);
  };

  int nt = KS >> 5;
  stage(0, 0);
  stage(1, (nt>1)?32:0);
  stage(2, (nt>2)?64:0);

  for (int tt = 0; tt < nt; ++tt){
    asm volatile("s_waitcnt vmcnt(8)" ::: "memory");
    __builtin_amdgcn_s_barrier();
    asm volatile("" ::: "memory");
    int bfi = tt % 3;
    const float* bW = &smW[bfi*2048];
    const float* bP = &smP[bfi*2048];
    f32x4 a0 = *(const f32x4*)&bW[RW0*32 + cw0];
    f32x4 a1 = *(const f32x4*)&bW[RW0*32 + cw1];
    f32x4 a2 = *(const f32x4*)&bW[RW0*32 + 512 + cw0];
    f32x4 a3 = *(const f32x4*)&bW[RW0*32 + 512 + cw1];
    f32x4 b0 = *(const f32x4*)&bP[RP0*32 + pc0];
    f32x4 b1 = *(const f32x4*)&bP[RP0*32 + pc1];
    f32x4 b2 = *(const f32x4*)&bP[RP0*32 + 512 + pc0];
    f32x4 b3 = *(const f32x4*)&bP[RP0*32 + 512 + pc1];
    f16x8 w0h, w0l, w1h, w1l, p0h, p0l, p1h, p1l;
    #pragma unroll
    for (int j=0;j<4;j++){
      f16 h;
      h=(f16)a0[j]; w0h[j]=h;   w0l[j]  =(f16)(a0[j]-(float)h);
      h=(f16)a1[j]; w0h[4+j]=h; w0l[4+j]=(f16)(a1[j]-(float)h);
      h=(f16)a2[j]; w1h[j]=h;   w1l[j]  =(f16)(a2[j]-(float)h);
      h=(f16)a3[j]; w1h[4+j]=h; w1l[4+j]=(f16)(a3[j]-(float)h);
      h=(f16)b0[j]; p0h[j]=h;   p0l[j]  =(f16)(b0[j]-(float)h);
      h=(f16)b1[j]; p0h[4+j]=h; p0l[4+j]=(f16)(b1[j]-(float)h);
      h=(f16)b2[j]; p1h[j]=h;   p1l[j]  =(f16)(b2[j]-(float)h);
      h=(f16)b3[j]; p1h[4+j]=h; p1l[4+j]=(f16)(b3[j]-(float)h);
    }
    acc[0][0] = __builtin_amdgcn_mfma_f32_16x16x32_f16(w0h, p0h, acc[0][0], 0,0,0);
    acc[0][1] = __builtin_amdgcn_mfma_f32_16x16x32_f16(w0h, p1h, acc[0][1], 0,0,0);
    acc[1][0] = __builtin_amdgcn_mfma_f32_16x16x32_f16(w1h, p0h, acc[1][0], 0,0,0);
    acc[1][1] = __builtin_amdgcn_mfma_f32_16x16x32_f16(w1h, p1h, acc[1][1], 0,0,0);
    acc[0][0] = __builtin_amdgcn_mfma_f32_16x16x32_f16(w0h, p0l, acc[0][0], 0,0,0);
    acc[0][1] = __builtin_amdgcn_mfma_f32_16x16x32_f16(w0h, p1l, acc[0][1], 0,0,0);
    acc[1][0] = __builtin_amdgcn_mfma_f32_16x16x32_f16(w1h, p0l, acc[1][0], 0,0,0);
    acc[1][1] = __builtin_amdgcn_mfma_f32_16x16x32_f16(w1h, p1l, acc[1][1], 0,0,0);
    acc[0][0] = __builtin_amdgcn_mfma_f32_16x16x32_f16(w0l, p0h, acc[0][0], 0,0,0);
    acc[0][1] = __builtin_amdgcn_mfma_f32_16x16x32_f16(w0l, p1h, acc[0][1], 0,0,0);
    acc[1][0] = __builtin_amdgcn_mfma_f32_16x16x32_f16(w1l, p0h, acc[1][0], 0,0,0);
    acc[1][1] = __builtin_amdgcn_mfma_f32_16x16x32_f16(w1l, p1h, acc[1][1], 0,0,0);
    __builtin_amdgcn_s_barrier();
    asm volatile("" ::: "memory");
    int kn = (tt+3 < nt) ? (tt+3)*32 : 0;
    stage(bfi, kn);
  }

  #pragma unroll
  for (int ri=0;ri<2;ri++)
  #pragma unroll
  for (int fc=0;fc<2;fc++)
  #pragma unroll
  for (int r=0;r<4;r++){
    int co = bn + wr*32 + ri*16 + (lane>>4)*4 + r;
    int m  = bm + wc*32 + fc*16 + (lane&15);
    if (m < Mreal)
      out[((size_t)blockIdx.z*sliceStride + m)*ldc + co] = acc[ri][fc][r];
  }
}

// ---------------- dt projection ----------------
__global__ __launch_bounds__(256) void k_dt(
    const float* __restrict__ xdp, const float* __restrict__ dtW,
    const float* __restrict__ dtB, float* __restrict__ dtb)
{
  __shared__ float smP[64*36];
  __shared__ float smW[64*36];
  int bn = blockIdx.x*64;
  int bm = blockIdx.y*64;
  int t = threadIdx.x, lane = t&63, wv = t>>6, wr = wv>>1, wc = wv&1;
  {
    int row = t>>2, c0 = (t&3)*8;
    #pragma unroll
    for (int j=0;j<8;j++){
      int cc = c0+j;
      float pv = 0.f;
      #pragma unroll
      for (int s=0;s<4;s++) pv += xdp[((size_t)(s*192) + bm+row)*64 + cc];
      smP[row*36 + cc] = pv;
      smW[row*36 + cc] = dtW[(size_t)(bn+row)*32 + cc];
    }
  }
  __syncthreads();
  int rA = lane&15, c = lane>>4;
  int c8 = c*8;
  f32x4 a0 = *(const f32x4*)&smW[(wr*32+rA)*36 + c8];
  f32x4 a1 = *(const f32x4*)&smW[(wr*32+rA)*36 + c8+4];
  f32x4 a2 = *(const f32x4*)&smW[(wr*32+16+rA)*36 + c8];
  f32x4 a3 = *(const f32x4*)&smW[(wr*32+16+rA)*36 + c8+4];
  f32x4 b0 = *(const f32x4*)&smP[(wc*32+rA)*36 + c8];
  f32x4 b1 = *(const f32x4*)&smP[(wc*32+rA)*36 + c8+4];
  f32x4 b2 = *(const f32x4*)&smP[(wc*32+16+rA)*36 + c8];
  f32x4 b3 = *(const f32x4*)&smP[(wc*32+16+rA)*36 + c8+4];
  f16x8 w0h, w0l, w1h, w1l, p0h, p0l, p1h, p1l;
  #pragma unroll
  for (int j=0;j<4;j++){
    f16 h;
    h=(f16)a0[j]; w0h[j]=h;   w0l[j]  =(f16)(a0[j]-(float)h);
    h=(f16)a1[j]; w0h[4+j]=h; w0l[4+j]=(f16)(a1[j]-(float)h);
    h=(f16)a2[j]; w1h[j]=h;   w1l[j]  =(f16)(a2[j]-(float)h);
    h=(f16)a3[j]; w1h[4+j]=h; w1l[4+j]=(f16)(a3[j]-(float)h);
    h=(f16)b0[j]; p0h[j]=h;   p0l[j]  =(f16)(b0[j]-(float)h);
    h=(f16)b1[j]; p0h[4+j]=h; p0l[4+j]=(f16)(b1[j]-(float)h);
    h=(f16)b2[j]; p1h[j]=h;   p1l[j]  =(f16)(b2[j]-(float)h);
    h=(f16)b3[j]; p1h[4+j]=h; p1l[4+j]=(f16)(b3[j]-(float)h);
  }
  f32x4 zz = {0.f,0.f,0.f,0.f};
  f32x4 acc[2][2];
  acc[0][0]=zz; acc[0][1]=zz; acc[1][0]=zz; acc[1][1]=zz;
  acc[0][0] = __builtin_amdgcn_mfma_f32_16x16x32_f16(w0h, p0h, acc[0][0], 0,0,0);
  acc[0][1] = __builtin_amdgcn_mfma_f32_16x16x32_f16(w0h, p1h, acc[0][1], 0,0,0);
  acc[1][0] = __builtin_amdgcn_mfma_f32_16x16x32_f16(w1h, p0h, acc[1][0], 0,0,0);
  acc[1][1] = __builtin_amdgcn_mfma_f32_16x16x32_f16(w1h, p1h, acc[1][1], 0,0,0);
  acc[0][0] = __builtin_amdgcn_mfma_f32_16x16x32_f16(w0h, p0l, acc[0][0], 0,0,0);
  acc[0][1] = __builtin_amdgcn_mfma_f32_16x16x32_f16(w0h, p1l, acc[0][1], 0,0,0);
  acc[1][0] = __builtin_amdgcn_mfma_f32_16x16x32_f16(w1h, p0l, acc[1][0], 0,0,0);
  acc[1][1] = __builtin_amdgcn_mfma_f32_16x16x32_f16(w1h, p1l, acc[1][1], 0,0,0);
  acc[0][0] = __builtin_amdgcn_mfma_f32_16x16x32_f16(w0l, p0h, acc[0][0], 0,0,0);
  acc[0][1] = __builtin_amdgcn_mfma_f32_16x16x32_f16(w0l, p1h, acc[0][1], 0,0,0);
  acc[1][0] = __builtin_amdgcn_mfma_f32_16x16x32_f16(w1l, p0h, acc[1][0], 0,0,0);
  acc[1][1] = __builtin_amdgcn_mfma_f32_16x16x32_f16(w1l, p1h, acc[1][1], 0,0,0);
  #pragma unroll
  for (int ri=0;ri<2;ri++)
  #pragma unroll
  for (int fc=0;fc<2;fc++)
  #pragma unroll
  for (int r=0;r<4;r++){
    int co = bn + wr*32 + ri*16 + (lane>>4)*4 + r;
    int m  = bm + wc*32 + fc*16 + (lane&15);
    if (m < 130)
      dtb[(size_t)m*1024 + co] = softplusf(acc[ri][fc][r] + dtB[co]);
  }
}

__global__ void k_maxpool2(const float* __restrict__ in, float* __restrict__ out, int BC, int H, int W){
  int Ho=H/2, Wo=W/2;
  int idx = blockIdx.x*blockDim.x + threadIdx.x;
  if (idx >= BC*Ho*Wo) return;
  int xo = idx % Wo; int yo = (idx / Wo) % Ho; int c = idx / (Wo*Ho);
  const float* p = in + ((size_t)c*H + 2*yo)*W + 2*xo;
  out[idx] = fmaxf(fmaxf(p[0],p[1]), fmaxf(p[W],p[W+1]));
}

// ---------------- Mamba ----------------
__global__ void k_build_tok(const float* __restrict__ p4, const float* __restrict__ cls,
                            float* __restrict__ hidp, float* __restrict__ residual){
  int idx = blockIdx.x*blockDim.x+threadIdx.x;
  if (idx >= 2*65*512) return;
  int d = idx % 512; int l = (idx/512)%65; int b = idx/(512*65);
  float v = (l==0) ? cls[d] : p4[((size_t)b*512+d)*64 + (l-1)];
  int row = b*65 + l;
  residual[(size_t)row*512 + d] = v;
  hidp[(size_t)row*512 + d] = v;
  #pragma unroll
  for (int s=1;s<8;s++) hidp[((size_t)(s*192) + row)*512 + d] = 0.f;
}

__global__ void k_add_ln(float* __restrict__ residual, const float* __restrict__ hidp,
                         const float* __restrict__ nw, const float* __restrict__ nb,
                         float* __restrict__ hs){
  int row = blockIdx.x;
  int t = threadIdx.x;
  __shared__ float red[256];
  size_t base = (size_t)row*512;
  float h0 = 0.f, h1 = 0.f;
  #pragma unroll
  for (int s=0;s<8;s++){
    h0 += hidp[((size_t)(s*192) + row)*512 + t];
    h1 += hidp[((size_t)(s*192) + row)*512 + 256 + t];
  }
  float v0 = residual[base + t]       + h0;
  float v1 = residual[base + 256 + t] + h1;
  residual[base+t]=v0; residual[base+256+t]=v1;
  red[t]=v0+v1; __syncthreads();
  for(int o=128;o>0;o>>=1){ if(t<o) red[t]+=red[t+o]; __syncthreads(); }
  float mean = red[0]/512.f; __syncthreads();
  float d0=v0-mean, d1=v1-mean;
  red[t]=d0*d0+d1*d1; __syncthreads();
  for(int o=128;o>0;o>>=1){ if(t<o) red[t]+=red[t+o]; __syncthreads(); }
  float rstd = rsqrtf(red[0]/512.f + 1e-5f);
  hs[base+t]     = d0*rstd*nw[t]     + nb[t];
  hs[base+256+t] = d1*rstd*nw[256+t] + nb[256+t];
}

__global__ void k_conv1d_silu(const float* __restrict__ xzp, const float* __restrict__ cw,
                              const float* __restrict__ cb, float* __restrict__ xc){
  int d = blockIdx.x*blockDim.x + threadIdx.x;
  int l = blockIdx.y, b = blockIdx.z;
  if (d>=1024) return;
  float acc = cb[d];
  #pragma unroll
  for(int k=0;k<4;k++){
    int lp = l-3+k;
    if (lp>=0){
      size_t r = (size_t)(b*65+lp);
      float xzv = xzp[r*2048 + d] + xzp[(r + 192)*2048 + d];
      acc = fmaf(xzv, cw[d*4+k], acc);
    }
  }
  xc[((size_t)(b*65+l))*1024 + d] = siluf(acc);
}

__global__ void k_scan(const float* __restrict__ dt, const float* __restrict__ xc,
                       const float* __restrict__ xdp, const float* __restrict__ xzp,
                       const float* __restrict__ Alog, const float* __restrict__ Dp,
                       float* __restrict__ gt){
  int gid = blockIdx.x*blockDim.x + threadIdx.x;
  if (gid >= 2*1024*16) return;
  int n = gid & 15;
  int d = (gid >> 4) & 1023;
  int b = gid >> 14;
  float A = -expf(Alog[d*16+n]);
  float Dv = Dp[d];
  float h = 0.f;
  for (int l=0;l<65;l++){
    size_t r = (size_t)(b*65+l);
    float dtv = dt[r*1024+d];
    float xcv = xc[r*1024+d];
    float Bn = 0.f, Cn = 0.f;
    #pragma unroll
    for (int s=0;s<4;s++){
      Bn += xdp[((size_t)(s*192) + r)*64 + 32 + n];
      Cn += xdp[((size_t)(s*192) + r)*64 + 48 + n];
    }
    h = fmaf(expf(dtv*A), h, dtv*xcv*Bn);
    float y = h*Cn;
    y += __shfl_xor(y, 1); y += __shfl_xor(y, 2);
    y += __shfl_xor(y, 4); y += __shfl_xor(y, 8);
    if (n==0){
      float zv = xzp[r*2048 + 1024 + d] + xzp[(r + 192)*2048 + 1024 + d];
      gt[r*1024+d] = (y + Dv*xcv) * siluf(zv);
    }
  }
}

__global__ void k_xsp(const float* __restrict__ hidp, float* __restrict__ xsp){
  int idx = blockIdx.x*blockDim.x+threadIdx.x;
  if (idx>=2*512*64) return;
  int j = idx & 63; int c = (idx>>6)&511; int b = idx>>15;
  int row = b*65 + 1 + j;
  float v = 0.f;
  #pragma unroll
  for (int s=0;s<8;s++) v += hidp[((size_t)(s*192) + row)*512 + c];
  xsp[idx] = v;
}

__global__ void k_conv1x1(const float* __restrict__ in, const float* __restrict__ w,
                          const float* __restrict__ bias, float* __restrict__ out){
  int hw = blockIdx.x*blockDim.x+threadIdx.x; if (hw>=128*128) return;
  int o = blockIdx.y, b = blockIdx.z;
  float acc = bias[o];
  #pragma unroll
  for(int c=0;c<32;c++) acc = fmaf(in[((size_t)(b*32+c))*16384 + hw], w[o*32+c], acc);
  out[((size_t)(b*4+o))*16384 + hw] = acc;
}

__global__ void k_resize16(const float* __restrict__ in, float* __restrict__ out){
  size_t idx = (size_t)blockIdx.x*blockDim.x + threadIdx.x;
  if (idx >= (size_t)2*4*2048*2048) return;
  int x = idx & 2047; int y = (int)((idx>>11)&2047); int c = (int)(idx>>22);
  float sx = ((float)x+0.5f)*(1.f/16.f) - 0.5f;
  float sy = ((float)y+0.5f)*(1.f/16.f) - 0.5f;
  int x0 = (int)floorf(sx); float fx = sx-(float)x0;
  int y0 = (int)floorf(sy); float fy = sy-(float)y0;
  int x0c = max(x0,0), x1c = min(x0+1,127);
  int y0c = max(y0,0), y1c = min(y0+1,127);
  const float* p = in + (size_t)c*16384;
  float v00=p[y0c*128+x0c], v01=p[y0c*128+x1c], v10=p[y1c*128+x0c], v11=p[y1c*128+x1c];
  out[idx] = (1.f-fy)*((1.f-fx)*v00 + fx*v01) + fy*((1.f-fx)*v10 + fx*v11);
}

// ---------------- host ----------------
#define MAX_A_ELEMS 524288

extern "C" void kernel_launch(void* const* d_in, const int* in_sizes, int n_in,
                              void* d_out, int out_size, void* d_ws, size_t ws_size,
                              hipStream_t stream) {
  const float* x        = (const float*)d_in[0];
  const float* masks    = (const float*)d_in[1];
  const float* ew1[4] = {(const float*)d_in[2],(const float*)d_in[6],(const float*)d_in[10],(const float*)d_in[14]};
  const float* eb1[4] = {(const float*)d_in[3],(const float*)d_in[7],(const float*)d_in[11],(const float*)d_in[15]};
  const float* ew2[4] = {(const float*)d_in[4],(const float*)d_in[8],(const float*)d_in[12],(const float*)d_in[16]};
  const float* eb2[4] = {(const float*)d_in[5],(const float*)d_in[9],(const float*)d_in[13],(const float*)d_in[17]};
  const float* cls      = (const float*)d_in[18];
  const float* norm_w   = (const float*)d_in[19];
  const float* norm_b   = (const float*)d_in[20];
  const float* in_proj  = (const float*)d_in[21];
  const float* conv1d_w = (const float*)d_in[22];
  const float* conv1d_b = (const float*)d_in[23];
  const float* x_proj   = (const float*)d_in[24];
  const float* dt_w     = (const float*)d_in[25];
  const float* dt_b     = (const float*)d_in[26];
  const float* A_log    = (const float*)d_in[27];
  const float* D_ssm    = (const float*)d_in[28];
  const float* out_proj = (const float*)d_in[29];
  const float* dup_w[4] = {(const float*)d_in[30],(const float*)d_in[36],(const float*)d_in[42],(const float*)d_in[48]};
  const float* dup_b[4] = {(const float*)d_in[31],(const float*)d_in[37],(const float*)d_in[43],(const float*)d_in[49]};
  const float* dw1[4]   = {(const float*)d_in[32],(const float*)d_in[38],(const float*)d_in[44],(const float*)d_in[50]};
  const float* db1[4]   = {(const float*)d_in[33],(const float*)d_in[39],(const float*)d_in[45],(const float*)d_in[51]};
  const float* dw2[4]   = {(const float*)d_in[34],(const float*)d_in[40],(const float*)d_in[46],(const float*)d_in[52]};
  const float* db2[4]   = {(const float*)d_in[35],(const float*)d_in[41],(const float*)d_in[47],(const float*)d_in[53]};
  const float* final_w  = (const float*)d_in[54];
  const float* final_b  = (const float*)d_in[55];
  float* out = (float*)d_out;

  float* W = (float*)d_ws;
  size_t off = 0;
  auto alloc = [&](size_t n){ float* p = W + off; off += n; return p; };

  float* Tre = alloc(32768);  float* Tim = alloc(32768);
  float* Fre = alloc(32768);  float* Fim = alloc(32768);
  float* Gre = alloc(196608); float* Gim = alloc(196608);
  float* xfreq = alloc(98304);
  float* tmpA = alloc(2097152);
  float* e1 = alloc(2097152);
  float* p1 = alloc(524288);
  float* e2 = alloc(1048576);
  float* p2 = alloc(262144);
  float* e3 = alloc(524288);
  float* p3 = alloc(131072);
  float* e4 = alloc(262144);
  float* p4 = alloc(65536);
  float* residual = alloc(66560);
  float* xsp = alloc(65536);
  float* tmpB = alloc(1048576);
  float* d4 = alloc(131072);
  float* d3 = alloc(262144);
  float* d2 = alloc(524288);
  float* d1 = alloc(1048576);
  float* fin = alloc(131072);
  (void)ws_size; (void)n_in; (void)in_sizes; (void)out_size;

  // ---- weight descriptor table (f16 conversions; small-conv entries unused but harmless) ----
  WAll wa;
  {
    const float* s[NWD] = { ew1[0], ew2[0], ew1[1], ew2[1], ew1[2], ew2[2], ew1[3], ew2[3],
                            dw1[0], dw2[0], dw1[1], dw2[1], dw1[2], dw2[2], dw1[3], dw2[3],
                            dup_w[0], dup_w[1], dup_w[2], dup_w[3] };
    const int N_[NWD]  = {64,64,128,128,256,256,512,512, 256,256,128,128,64,64,32,32, 1024,512,256,128};
    const int CI_[NWD] = {3,64,64,128,128,256,256,512, 768,256,384,128,192,64,96,32, 512,256,128,64};
    const int U_[NWD]  = {0,0,0,0,0,0,0,0, 0,0,0,0,0,0,0,0, 256,128,64,32};
    int cacc = 0;
    for (int i=0;i<NWD;i++){
      wa.src[i]=s[i]; wa.N[i]=N_[i]; wa.up[i]=U_[i]; wa.ci[i]=CI_[i];
      int cip = (CI_[i]+31)&~31;
      wa.cip[i] = cip;
      wa.Kp[i] = U_[i] ? CI_[i] : 9*cip;
      wa.cum[i]=cacc;
      int Np=(N_[i]+63)&~63;
      cacc += Np*wa.Kp[i];
    }
    wa.cum[NWD]=cacc;
  }
  int wtotal = wa.cum[NWD];

  // ---- scratch in d_out (all dead before k_resize16 rewrites it) ----
  f16* q = (f16*)d_out;
  f16* Ahi = q; q += MAX_A_ELEMS;
  f16* Alo = q; q += MAX_A_ELEMS;
  f16* Ball_h = q; q += wtotal;
  f16* Ball_l = q; q += wtotal;
  float* fb = (float*)q;
  size_t foff = 0;
  auto falloc = [&](size_t n){ float* p = fb + foff; foff += n; return p; };
  float* convpart = falloc(2097152);
  float* Af32 = falloc(7340032);          // im2col fp32 A (max d3a: 2048 x 3456)
  float* xzp  = falloc(2*192*2048);
  float* xdp  = falloc(4*192*64);
  float* hidp = falloc(8*192*512);
  float* hs   = falloc(192*512);
  float* xc   = falloc(192*1024);
  float* gt   = falloc(192*1024);
  float* dtb  = falloc(192*1024);

  hipLaunchKernelGGL(k_wcvt_all, dim3((wtotal+255)/256), dim3(256), 0, stream, wa, wtotal, Ball_h, Ball_l);

  // ---- frequency band split ----
  hipLaunchKernelGGL(k_dft_rows, dim3(128,2), dim3(128), 0, stream, x, Tre, Tim);
  hipLaunchKernelGGL(k_dft_cols, dim3(128,2), dim3(128), 0, stream, Tre, Tim, Fre, Fim);
  hipLaunchKernelGGL(k_idft_cols, dim3(128,3,2), dim3(128), 0, stream, Fre, Fim, masks, Gre, Gim);
  hipLaunchKernelGGL(k_idft_rows, dim3(128,3,2), dim3(128), 0, stream, Gre, Gim, xfreq);

  auto ctz = [](int v){ int s=0; while(!(v&1)){v>>=1;s++;} return s; };
  // big-image convs: proven implicit-GEMM (S=1)
  auto conv_ig = [&](const float* i1,int C1,const float* i2,int C2,
                     int widx, const float* bias, float* o, int Co, int H){
    int Wd = H;
    int Ci = C1+C2, Cip = (Ci+31)&~31;
    int M = 2*H*Wd, Np = (Co+63)&~63;
    int wsh = ctz(Wd), hwsh = ctz(H*Wd);
    int civ = Ci < 32 ? Ci : 32;
    const f16* bh = Ball_h + wa.cum[widx];
    const f16* bl = Ball_l + wa.cum[widx];
    dim3 g(M/64, Np/64);
    if (Wd >= 64)
      hipLaunchKernelGGL((k_conv_ig<25>), g, dim3(256), 0, stream, i1,C1,i2,C2,bh,bl,bias,o,Co,H,Wd,wsh,hwsh,Cip,civ);
    else if (Wd == 32)
      hipLaunchKernelGGL((k_conv_ig<17>), g, dim3(256), 0, stream, i1,C1,i2,C2,bh,bl,bias,o,Co,H,Wd,wsh,hwsh,Cip,civ);
    else
      hipLaunchKernelGGL((k_conv_ig<14>), g, dim3(256), 0, stream, i1,C1,i2,C2,bh,bl,bias,o,Co,H,Wd,wsh,hwsh,Cip,civ);
  };
  // small-image convs: fp32 im2col + split-K MFMA GEMM (raw fp32 weights) + creduce
  auto conv_sk = [&](const float* i1,int C1,const float* i2,int C2,
                     const float* wraw, const float* bias, float* o, int Co, int H, int S){
    int Wd = H;
    int Ci = C1+C2, K = Ci*9;
    int M = 2*H*Wd;
    int wsh = ctz(Wd), hwsh = ctz(H*Wd);
    hipLaunchKernelGGL(k_im2col32, dim3((K+255)/256, M), dim3(256), 0, stream,
                       i1, C1, i2, C2, H, Wd, wsh, hwsh, K, Af32);
    int KS = K / S;
    hipLaunchKernelGGL(k_gemm_w32s, dim3(M/64, Co/64, S), dim3(256), 0, stream,
                       wraw, K, Af32, K, convpart, Co, KS, M, Co, M);
    hipLaunchKernelGGL(k_creduce, dim3((M*Co+255)/256), dim3(256), 0, stream,
                       convpart, bias, o, M, Co, ctz(M), ctz(Co), hwsh, S);
  };
  auto up_bf = [&](const float* in, int widx, const float* bias, float* o,
                   int Ci,int Co,int Hi){
    int Kp=Ci, N=4*Co;
    int M=2*Hi*Hi;
    int wsh=ctz(Hi), hwsh=ctz(Hi*Hi);
    const f16* bh = Ball_h + wa.cum[widx];
    const f16* bl = Ball_l + wa.cum[widx];
    hipLaunchKernelGGL(k_im2col, dim3((Kp+255)/256, M), dim3(256), 0, stream,
                       in, Ci, Hi, Hi, wsh, hwsh, Ci, Kp, Ahi, Alo);
    hipLaunchKernelGGL(k_gemm_hl, dim3(M/64, N/64), dim3(256), 0, stream,
                       bh, bl, Ahi, Alo, bias, o, N, Kp, wsh, hwsh, Co);
  };

  // ---- encoder ----
  conv_ig(xfreq,3,  nullptr,0, 0, eb1[0], tmpA, 64, 128);
  conv_ig(tmpA,64,  nullptr,0, 1, eb2[0], e1,   64, 128);
  hipLaunchKernelGGL(k_maxpool2, dim3((2*64*64*64+255)/256), dim3(256), 0, stream, e1, p1, 2*64, 128,128);
  conv_ig(p1,64,    nullptr,0, 2, eb1[1], tmpA, 128, 64);
  conv_ig(tmpA,128, nullptr,0, 3, eb2[1], e2,   128, 64);
  hipLaunchKernelGGL(k_maxpool2, dim3((2*128*32*32+255)/256), dim3(256), 0, stream, e2, p2, 2*128, 64,64);
  conv_sk(p2,128,   nullptr,0, ew1[2], eb1[2], tmpA, 256, 32, 4);
  conv_sk(tmpA,256, nullptr,0, ew2[2], eb2[2], e3,   256, 32, 4);
  hipLaunchKernelGGL(k_maxpool2, dim3((2*256*16*16+255)/256), dim3(256), 0, stream, e3, p3, 2*256, 32,32);
  conv_sk(p3,256,   nullptr,0, ew1[3], eb1[3], tmpA, 512, 16, 8);
  conv_sk(tmpA,512, nullptr,0, ew2[3], eb2[3], e4,   512, 16, 8);
  hipLaunchKernelGGL(k_maxpool2, dim3((2*512*8*8+255)/256), dim3(256), 0, stream, e4, p4, 2*512, 16,16);

  // ---- mamba stack ----
  hipLaunchKernelGGL(k_build_tok, dim3((2*65*512+255)/256), dim3(256), 0, stream, p4, cls, hidp, residual);
  for (int l=0;l<24;l++){
    const float* nw   = norm_w   + (size_t)l*512;
    const float* nb   = norm_b   + (size_t)l*512;
    const float* inW  = in_proj  + (size_t)l*2048*512;
    const float* cw   = conv1d_w + (size_t)l*1024*4;
    const float* cb   = conv1d_b + (size_t)l*1024;
    const float* xpW  = x_proj   + (size_t)l*64*1024;
    const float* dtW  = dt_w     + (size_t)l*1024*32;
    const float* dtB  = dt_b     + (size_t)l*1024;
    const float* Alg  = A_log    + (size_t)l*1024*16;
    const float* Dp   = D_ssm    + (size_t)l*1024;
    const float* outW = out_proj + (size_t)l*512*1024;

    hipLaunchKernelGGL(k_add_ln, dim3(130), dim3(256), 0, stream, residual, hidp, nw, nb, hs);
    hipLaunchKernelGGL(k_gemm_w32s, dim3(3,32,2), dim3(256), 0, stream,
                       inW, 512, hs, 512, xzp, 2048, 256, 130, 2048, 192);
    hipLaunchKernelGGL(k_conv1d_silu, dim3(4,65,2), dim3(256), 0, stream, xzp, cw, cb, xc);
    hipLaunchKernelGGL(k_gemm_w32s, dim3(3,1,4), dim3(256), 0, stream,
                       xpW, 1024, xc, 1024, xdp, 64, 256, 130, 64, 192);
    hipLaunchKernelGGL(k_dt, dim3(16,3), dim3(256), 0, stream, xdp, dtW, dtB, dtb);
    hipLaunchKernelGGL(k_scan, dim3(128), dim3(256), 0, stream, dtb, xc, xdp, xzp, Alg, Dp, gt);
    hipLaunchKernelGGL(k_gemm_w32s, dim3(3,8,8), dim3(256), 0, stream,
                       outW, 1024, gt, 1024, hidp, 512, 128, 130, 512, 192);
  }
  hipLaunchKernelGGL(k_xsp, dim3((2*512*64+255)/256), dim3(256), 0, stream, hidp, xsp);

  // ---- decoder ----
  up_bf(xsp, 16, dup_b[0], tmpB, 512, 256, 8);
  conv_sk(e4,512, tmpB,256, dw1[0], db1[0], tmpA, 256, 16, 8);
  conv_sk(tmpA,256, nullptr,0, dw2[0], db2[0], d4, 256, 16, 8);
  up_bf(d4, 17, dup_b[1], tmpB, 256, 128, 16);
  conv_sk(e3,256, tmpB,128, dw1[1], db1[1], tmpA, 128, 32, 4);
  conv_sk(tmpA,128, nullptr,0, dw2[1], db2[1], d3, 128, 32, 4);
  up_bf(d3, 18, dup_b[2], tmpB, 128, 64, 32);
  conv_ig(e2,128, tmpB,64, 12, db1[2], tmpA, 64, 64);
  conv_ig(tmpA,64, nullptr,0, 13, db2[2], d2, 64, 64);
  up_bf(d2, 19, dup_b[3], tmpB, 64, 32, 64);
  conv_ig(e1,64, tmpB,32, 14, db1[3], tmpA, 32, 128);
  conv_ig(tmpA,32, nullptr,0, 15, db2[3], d1, 32, 128);

  // ---- head ----
  hipLaunchKernelGGL(k_conv1x1, dim3((16384+255)/256, 4, 2), dim3(256), 0, stream, d1, final_w, final_b, fin);
  hipLaunchKernelGGL(k_resize16, dim3((size_t)(2*4*2048*2048)/256), dim3(256), 0, stream, fin, out);
}

// Round 15
// 3117.894 us; speedup vs baseline: 1.0481x; 1.0008x over previous
//
#include <hip/hip_runtime.h>
#include <math.h>

#define PI_F 3.14159265358979323846f
typedef _Float16 f16;
typedef __attribute__((ext_vector_type(8))) _Float16 f16x8;
typedef __attribute__((ext_vector_type(4))) float f32x4;

__device__ __forceinline__ float siluf(float x){ return x / (1.f + expf(-x)); }
__device__ __forceinline__ float softplusf(float x){ return fmaxf(x,0.f) + log1pf(expf(-fabsf(x))); }
__device__ __forceinline__ void f2hl(float v, f16& hi, f16& lo){
  hi = (f16)v;
  lo = (f16)(v - (float)hi);
}

// ---------------- DFT band filtering ----------------
__global__ void k_dft_rows(const float* __restrict__ x, float* __restrict__ Tre, float* __restrict__ Tim){
  int v = threadIdx.x; int y = blockIdx.x; int b = blockIdx.y;
  __shared__ float cs[128], sn[128];
  float ang = -2.f*PI_F*(float)v/128.f;
  cs[v]=cosf(ang); sn[v]=sinf(ang);
  __syncthreads();
  const float* row = x + (b*128+y)*128;
  float re=0.f, im=0.f;
  for(int n=0;n<128;n++){ float xv=row[n]; int ph=(v*n)&127; re=fmaf(xv,cs[ph],re); im=fmaf(xv,sn[ph],im); }
  int o=(b*128+y)*128+v; Tre[o]=re; Tim[o]=im;
}
__global__ void k_dft_cols(const float* __restrict__ Tre, const float* __restrict__ Tim,
                           float* __restrict__ Fre, float* __restrict__ Fim){
  int v=threadIdx.x; int u=blockIdx.x; int b=blockIdx.y;
  __shared__ float cs[128], sn[128];
  float ang=-2.f*PI_F*(float)v/128.f; cs[v]=cosf(ang); sn[v]=sinf(ang);
  __syncthreads();
  float re=0.f,im=0.f;
  for(int y=0;y<128;y++){
    int ph=(u*y)&127; float c=cs[ph], s=sn[ph];
    int o=(b*128+y)*128+v;
    float tr=Tre[o], ti=Tim[o];
    re += tr*c - ti*s; im += tr*s + ti*c;
  }
  int o=(b*128+u)*128+v; Fre[o]=re; Fim[o]=im;
}
__global__ void k_idft_cols(const float* __restrict__ Fre,const float* __restrict__ Fim,
                            const float* __restrict__ mask, float* __restrict__ Gre,float* __restrict__ Gim){
  int v=threadIdx.x; int y=blockIdx.x; int m=blockIdx.y; int b=blockIdx.z;
  __shared__ float cs[128], sn[128];
  float ang=-2.f*PI_F*(float)v/128.f; cs[v]=cosf(ang); sn[v]=sinf(ang);
  __syncthreads();
  float re=0.f,im=0.f;
  for(int u=0;u<128;u++){
    int ph=(u*y)&127; float c=cs[ph], s=sn[ph];
    float w = mask[(m*128+u)*128+v];
    int o=(b*128+u)*128+v;
    float fr=Fre[o]*w, fi=Fim[o]*w;
    re += fr*c + fi*s;
    im += fi*c - fr*s;
  }
  int o=((b*3+m)*128+y)*128+v;
  Gre[o]=re*(1.f/128.f); Gim[o]=im*(1.f/128.f);
}
__global__ void k_idft_rows(const float* __restrict__ Gre,const float* __restrict__ Gim, float* __restrict__ xf){
  int xc=threadIdx.x; int y=blockIdx.x; int m=blockIdx.y; int b=blockIdx.z;
  __shared__ float cs[128], sn[128];
  float ang=-2.f*PI_F*(float)xc/128.f; cs[xc]=cosf(ang); sn[xc]=sinf(ang);
  __syncthreads();
  float re=0.f;
  const float* gr=Gre+((b*3+m)*128+y)*128;
  const float* gi=Gim+((b*3+m)*128+y)*128;
  for(int v=0;v<128;v++){
    int ph=(v*xc)&127;
    re += gr[v]*cs[ph] + gi[v]*sn[ph];
  }
  xf[((b*3+m)*128+y)*128+xc] = re*(1.f/128.f);
}

// ---------------- batched weight conversion ----------------
#define NWD 20
struct WAll {
  const float* src[NWD];
  int N[NWD], Kp[NWD], up[NWD], ci[NWD], cip[NWD];
  int cum[NWD+1];
};
__global__ void k_wcvt_all(WAll d, int total, f16* __restrict__ bh, f16* __restrict__ bl){
  int gid = blockIdx.x*256 + threadIdx.x;
  if (gid >= total) return;
  int li = gid; const float* src = d.src[0];
  int N=d.N[0], Kp=d.Kp[0], up=d.up[0], Ci=d.ci[0], cip=d.cip[0];
  #pragma unroll
  for (int j=1;j<NWD;j++){
    if (gid >= d.cum[j]){
      li = gid - d.cum[j]; src=d.src[j]; N=d.N[j];Kp=d.Kp[j];up=d.up[j];Ci=d.ci[j];cip=d.cip[j];
    }
  }
  int n = li / Kp, k = li - n*Kp;
  float v = 0.f;
  if (up){
    int o = n>>2, p=(n>>1)&1, q=n&1;
    if (k < Ci) v = src[(((size_t)k*up + o)*2 + p)*2 + q];
  } else {
    int tap = k / cip, cc = k - tap*cip;
    if (n < N && cc < Ci) v = src[((size_t)n*Ci + cc)*9 + tap];
  }
  f16 h,l; f2hl(v,h,l);
  bh[gid]=h; bl[gid]=l;
}

// im2col for up-convs (f16 hi/lo): rows of M=B*H*W, k=ci
__global__ void k_im2col(const float* __restrict__ in1, int C1,
                         int H, int W, int wsh, int hwsh, int K, int Kp,
                         f16* __restrict__ Ah, f16* __restrict__ Al){
  int k = blockIdx.x*256 + threadIdx.x;
  int lm = blockIdx.y;
  if (k >= Kp) return;
  float val = 0.f;
  if (k < K){
    int m = lm;
    int b = m >> hwsh;
    int hw = m & ((1<<hwsh)-1);
    int y = hw >> wsh;
    int x = hw & (W-1);
    val = in1[(((size_t)b*C1 + k)*H + y)*W + x];
  }
  f16 h,l; f2hl(val,h,l);
  Ah[(size_t)lm*Kp + k] = h; Al[(size_t)lm*Kp + k] = l;
}

// im2col fp32 (3x3, pad 1), concat-aware: A[m*K + k], k = ci*9 + (ky*3+kx)
__global__ void k_im2col32(const float* __restrict__ in1, int C1,
                           const float* __restrict__ in2, int C2,
                           int H, int W, int wsh, int hwsh, int K,
                           float* __restrict__ A){
  int k = blockIdx.x*256 + threadIdx.x;
  int m = blockIdx.y;
  if (k >= K) return;
  int ci = k/9; int tt = k - ci*9;
  int dy = tt/3 - 1, dx = tt - (tt/3)*3 - 1;
  int b = m >> hwsh;
  int hw = m & ((1<<hwsh)-1);
  int y = (hw >> wsh) + dy;
  int x = (hw & (W-1)) + dx;
  float val = 0.f;
  if (y >= 0 && y < H && x >= 0 && x < W){
    val = (ci < C1) ? in1[(((size_t)b*C1 + ci)*H + y)*W + x]
                    : in2[(((size_t)b*C2 + (ci-C1))*H + y)*W + x];
  }
  A[(size_t)m*K + k] = val;
}

#define GLLDS(gp, ls) __builtin_amdgcn_global_load_lds( \
    (const __attribute__((address_space(1))) void*)(gp), \
    (__attribute__((address_space(3))) void*)(ls), 16, 0, 0)

// ---------------- implicit-GEMM conv3x3 (S=1 only; proven path for H>=64) ----------------
template<int NL>
__global__ __launch_bounds__(256) void k_conv_ig(
    const float* __restrict__ in1, int C1, const float* __restrict__ in2, int C2,
    const f16* __restrict__ Wh, const f16* __restrict__ Wl,
    const float* __restrict__ bias, float* __restrict__ out,
    int Co, int H, int W, int wsh, int hwsh, int Cip, int civ)
{
  __shared__ __align__(16) float smI[2*6464];
  __shared__ __align__(16) f16 smW[3*2*2048];
  const int HW = 1<<hwsh;
  const int tw = (W<64)?W:64;
  const int twsh = (wsh<6)?wsh:6;
  const int R = 64>>twsh;
  const int RT = R+2, TWD = tw+2;
  const int nspat = RT*TWD;
  const int CS = ((nspat+3)&~3)+2;
  const int total = nspat*32;
  const int nslab = Cip>>5;
  const int nsteps = 9*nslab;
  const int Kp = 9*Cip;

  int bn = blockIdx.y*64;
  int bm = blockIdx.x*64;
  int t = threadIdx.x;
  int lane = t&63, wv = t>>6;
  int wr = wv>>1, wc = wv&1;

  int b  = bm >> hwsh;
  int hw0 = bm & (HW-1);
  int y0 = hw0 >> wsh;
  int x0 = hw0 & (W-1);

  float bv[2][4];
  {
    int cb = bn + wr*32 + (lane>>4)*4;
    #pragma unroll
    for (int ri=0;ri<2;ri++)
      #pragma unroll
      for (int r=0;r<4;r++){
        int co = cb + ri*16 + r;
        bv[ri][r] = bias[co < Co ? co : Co-1];
      }
    asm volatile("s_waitcnt vmcnt(0)" ::: "memory");
  }

  int goff[NL], loff[NL];
  {
    int ci = 0, s = t;
    if (s >= nspat){ s -= nspat; ci++; }
    if (s >= nspat){ s -= nspat; ci++; }
    #pragma unroll
    for (int j=0;j<NL;j++){
      int rr_=0, sx=s;
      #pragma unroll
      for (int q=0;q<5;q++){ if (sx>=TWD){ sx-=TWD; rr_++; } }
      int gy = y0 - 1 + rr_;
      int gx = x0 - 1 + sx;
      int idx = t + j*256;
      bool intile = (idx < total);
      bool ok = intile && (ci < civ) && (gy>=0) && (gy<H) && (gx>=0) && (gx<W);
      goff[j] = ok ? (ci*HW + gy*W + gx) : -1;
      loff[j] = intile ? (ci*CS + rr_*TWD + sx) : -1;
      s += 256;
      if (s >= nspat){ s -= nspat; ci++; }
      if (s >= nspat){ s -= nspat; ci++; }
      if (s >= nspat){ s -= nspat; ci++; }
    }
  }

  int rr = lane >> 2;
  int cg = (lane & 3) ^ ((lane >> 3) & 3);
  size_t gW = (size_t)(bn + wv*16 + rr)*Kp + cg*8;
  int lb = wv*512;
  auto stage = [&](int bfi, int k0){
    GLLDS(Wh + gW + k0, &smW[(bfi*2+0)*2048 + lb]);
    GLLDS(Wl + gW + k0, &smW[(bfi*2+1)*2048 + lb]);
  };

  int rA = lane & 15, c = lane >> 4;
  int RW = wr*32 + rA; int sW = (RW>>1)&3;
  int offW = RW*32 + 8*(c ^ sW);
  int lp0 = wc*32 + rA, lp1 = lp0 + 16;
  int sid0 = ((lp0>>twsh)+1)*TWD + (lp0 & (tw-1)) + 1;
  int sid1 = ((lp1>>twsh)+1)*TWD + (lp1 & (tw-1)) + 1;
  int cbase = c*8*CS;
  int csj[8];
  #pragma unroll
  for (int j=0;j<8;j++) csj[j] = j*CS;

  auto srcptr = [&](int sl) -> const float* {
    int cbeg = sl*32;
    return (cbeg < C1) ? in1 + ((size_t)(b*C1 + cbeg))*HW
                       : in2 + ((size_t)(b*C2 + (cbeg - C1)))*HW;
  };

  float rin[NL];
  {
    const float* sp = srcptr(0);
    #pragma unroll
    for (int j=0;j<NL;j++) rin[j] = sp[goff[j] < 0 ? 0 : goff[j]];
  }
  stage(0, 0);
  stage(1, Cip);
  stage(2, 2*Cip);
  asm volatile("s_waitcnt vmcnt(6)" ::: "memory");
  #pragma unroll
  for (int j=0;j<NL;j++) if (loff[j] >= 0) smI[loff[j]] = (goff[j] < 0) ? 0.f : rin[j];
  asm volatile("s_waitcnt lgkmcnt(0)" ::: "memory");
  __builtin_amdgcn_s_barrier();
  asm volatile("" ::: "memory");
  if (nslab > 1){
    const float* sp = srcptr(1);
    #pragma unroll
    for (int j=0;j<NL;j++) rin[j] = sp[goff[j] < 0 ? 0 : goff[j]];
  }

  f32x4 zz = {0.f,0.f,0.f,0.f};
  f32x4 acc[2][2];
  acc[0][0]=zz; acc[0][1]=zz; acc[1][0]=zz; acc[1][1]=zz;

  int tcur = 0, scur = 0;
  int stp_t3 = 3, stp_s3 = 0;
  int bfi = 0;

  for (int step = 0; step < nsteps; ++step){
    if (tcur == 0 && step > 0){
      asm volatile("s_waitcnt vmcnt(6)" ::: "memory");
      int wb = (scur & 1)*6464;
      #pragma unroll
      for (int j=0;j<NL;j++) if (loff[j] >= 0) smI[wb + loff[j]] = (goff[j] < 0) ? 0.f : rin[j];
      asm volatile("s_waitcnt lgkmcnt(0)" ::: "memory");
      __builtin_amdgcn_s_barrier();
      asm volatile("" ::: "memory");
      if (scur + 1 < nslab){
        const float* sp = srcptr(scur+1);
        #pragma unroll
        for (int j=0;j<NL;j++) rin[j] = sp[goff[j] < 0 ? 0 : goff[j]];
      }
    }
    if (tcur < 3 && (scur + 1 < nslab)){
      if constexpr (NL == 25) asm volatile("s_waitcnt vmcnt(29)" ::: "memory");
      else if constexpr (NL == 17) asm volatile("s_waitcnt vmcnt(21)" ::: "memory");
      else asm volatile("s_waitcnt vmcnt(18)" ::: "memory");
    } else {
      asm volatile("s_waitcnt vmcnt(4)" ::: "memory");
    }
    __builtin_amdgcn_s_barrier();
    asm volatile("" ::: "memory");

    const f16* bW = &smW[bfi*4096];
    f16x8 w0h = *(const f16x8*)&bW[offW];
    f16x8 w1h = *(const f16x8*)&bW[offW + 512];
    f16x8 w0l = *(const f16x8*)&bW[2048 + offW];
    f16x8 w1l = *(const f16x8*)&bW[2048 + offW + 512];

    int t3v = (tcur >= 6) ? 2 : ((tcur >= 3) ? 1 : 0);
    int doff = (t3v - 1)*TWD + (tcur - 3*t3v) - 1;
    int ib = (scur & 1)*6464 + cbase;
    f16x8 p0h, p0l, p1h, p1l;
    #pragma unroll
    for (int j=0;j<8;j++){
      float v0 = smI[ib + csj[j] + sid0 + doff];
      float v1 = smI[ib + csj[j] + sid1 + doff];
      f16 h0 = (f16)v0; p0h[j] = h0; p0l[j] = (f16)(v0 - (float)h0);
      f16 h1 = (f16)v1; p1h[j] = h1; p1l[j] = (f16)(v1 - (float)h1);
    }
    acc[0][0] = __builtin_amdgcn_mfma_f32_16x16x32_f16(w0h, p0h, acc[0][0], 0,0,0);
    acc[0][1] = __builtin_amdgcn_mfma_f32_16x16x32_f16(w0h, p1h, acc[0][1], 0,0,0);
    acc[1][0] = __builtin_amdgcn_mfma_f32_16x16x32_f16(w1h, p0h, acc[1][0], 0,0,0);
    acc[1][1] = __builtin_amdgcn_mfma_f32_16x16x32_f16(w1h, p1h, acc[1][1], 0,0,0);
    acc[0][0] = __builtin_amdgcn_mfma_f32_16x16x32_f16(w0h, p0l, acc[0][0], 0,0,0);
    acc[0][1] = __builtin_amdgcn_mfma_f32_16x16x32_f16(w0h, p1l, acc[0][1], 0,0,0);
    acc[1][0] = __builtin_amdgcn_mfma_f32_16x16x32_f16(w1h, p0l, acc[1][0], 0,0,0);
    acc[1][1] = __builtin_amdgcn_mfma_f32_16x16x32_f16(w1h, p1l, acc[1][1], 0,0,0);
    acc[0][0] = __builtin_amdgcn_mfma_f32_16x16x32_f16(w0l, p0h, acc[0][0], 0,0,0);
    acc[0][1] = __builtin_amdgcn_mfma_f32_16x16x32_f16(w0l, p1h, acc[0][1], 0,0,0);
    acc[1][0] = __builtin_amdgcn_mfma_f32_16x16x32_f16(w1l, p0h, acc[1][0], 0,0,0);
    acc[1][1] = __builtin_amdgcn_mfma_f32_16x16x32_f16(w1l, p1h, acc[1][1], 0,0,0);

    __builtin_amdgcn_s_barrier();
    asm volatile("" ::: "memory");
    int k0 = (stp_s3 < nslab) ? (stp_t3*Cip + stp_s3*32) : 0;
    stage(bfi, k0);
    if (++stp_t3 == 9){ stp_t3 = 0; stp_s3++; }
    bfi = (bfi == 2) ? 0 : bfi + 1;
    if (++tcur == 9){ tcur = 0; scur++; }
  }

  #pragma unroll
  for (int ri=0;ri<2;ri++)
  #pragma unroll
  for (int fc=0;fc<2;fc++)
  #pragma unroll
  for (int r=0;r<4;r++){
    int co = bn + wr*32 + ri*16 + (lane>>4)*4 + r;
    int pm = bm + wc*32 + fc*16 + (lane&15);
    if (co < Co){
      float v = acc[ri][fc][r] + bv[ri][r];
      v = fmaxf(v, 0.f);
      int hw = pm & (HW-1);
      out[((size_t)b*Co + co)*HW + hw] = v;
    }
  }
}

// sum S partial slices + bias + relu -> NCHW
__global__ void k_creduce(const float* __restrict__ part, const float* __restrict__ bias,
                          float* __restrict__ out, int M, int Np, int msh, int cosh, int hwsh, int S){
  int i = blockIdx.x*256 + threadIdx.x;
  int Co = 1<<cosh;
  if (i >= M*Co) return;
  int co = i >> msh, m = i & (M-1);
  float v = bias[co];
  for (int s=0;s<S;s++) v += part[((size_t)s*M + m)*Np + co];
  v = fmaxf(v, 0.f);
  int HW = 1<<hwsh;
  int b = m >> hwsh, hw = m & (HW-1);
  out[((size_t)b*Co + co)*HW + hw] = v;
}

// ---------------- pipelined split-f16 MFMA GEMM (up-convs, scatter epilogue) ----------------
__global__ __launch_bounds__(256) void k_gemm_hl(
    const f16* __restrict__ Wh, const f16* __restrict__ Wl,
    const f16* __restrict__ Ph, const f16* __restrict__ Pl,
    const float* __restrict__ bias, float* __restrict__ out,
    int N, int Kp, int wsh, int hwsh, int Co)
{
  __shared__ __align__(16) f16 sm[3*4*2048];
  int bn = blockIdx.y*64;
  int bm = blockIdx.x*64;
  int t = threadIdx.x;
  int lane = t & 63, wv = t >> 6;
  int wr = wv >> 1, wc = wv & 1;

  float bv[2][4];
  {
    int cb = bn + wr*32 + (lane>>4)*4;
    #pragma unroll
    for (int ri=0;ri<2;ri++)
      #pragma unroll
      for (int r=0;r<4;r++){
        int co = cb + ri*16 + r;
        int idx = co>>2, lim = N>>2;
        if (idx >= lim) idx = lim-1;
        bv[ri][r] = bias[idx];
      }
  }
  asm volatile("s_waitcnt vmcnt(0)" ::: "memory");

  int rr = lane >> 2;
  int cg = (lane & 3) ^ ((lane >> 3) & 3);
  size_t gW = (size_t)(bn + wv*16 + rr)*Kp + cg*8;
  size_t gP = (size_t)(bm + wv*16 + rr)*Kp + cg*8;
  int lb = wv*512;

  int rA = lane & 15, c = lane >> 4;
  int RW = wr*32 + rA; int sW = (RW>>1)&3;
  int offW = RW*32 + 8*(c ^ sW);
  int RP = wc*32 + rA; int sP = (RP>>1)&3;
  int offP = RP*32 + 8*(c ^ sP);

  f32x4 zz = {0.f,0.f,0.f,0.f};
  f32x4 acc[2][2];
  acc[0][0]=zz; acc[0][1]=zz; acc[1][0]=zz; acc[1][1]=zz;

  auto stage = [&](int bfi, int kk){
    GLLDS(Wh + gW + kk, &sm[(bfi*4+0)*2048 + lb]);
    GLLDS(Wl + gW + kk, &sm[(bfi*4+1)*2048 + lb]);
    GLLDS(Ph + gP + kk, &sm[(bfi*4+2)*2048 + lb]);
    GLLDS(Pl + gP + kk, &sm[(bfi*4+3)*2048 + lb]);
  };

  int nt = Kp >> 5;
  stage(0, 0);
  stage(1, (nt>1)?32:0);
  stage(2, (nt>2)?64:0);

  for (int tt = 0; tt < nt; ++tt){
    asm volatile("s_waitcnt vmcnt(8)" ::: "memory");
    __builtin_amdgcn_s_barrier();
    asm volatile("" ::: "memory");
    int bfi = tt % 3;
    int base = bfi*8192;
    f16x8 w0h = *(const f16x8*)&sm[base + offW];
    f16x8 w1h = *(const f16x8*)&sm[base + offW + 512];
    f16x8 w0l = *(const f16x8*)&sm[base + 2048 + offW];
    f16x8 w1l = *(const f16x8*)&sm[base + 2048 + offW + 512];
    f16x8 p0h = *(const f16x8*)&sm[base + 4096 + offP];
    f16x8 p1h = *(const f16x8*)&sm[base + 4096 + offP + 512];
    f16x8 p0l = *(const f16x8*)&sm[base + 6144 + offP];
    f16x8 p1l = *(const f16x8*)&sm[base + 6144 + offP + 512];
    acc[0][0] = __builtin_amdgcn_mfma_f32_16x16x32_f16(w0h, p0h, acc[0][0], 0,0,0);
    acc[0][1] = __builtin_amdgcn_mfma_f32_16x16x32_f16(w0h, p1h, acc[0][1], 0,0,0);
    acc[1][0] = __builtin_amdgcn_mfma_f32_16x16x32_f16(w1h, p0h, acc[1][0], 0,0,0);
    acc[1][1] = __builtin_amdgcn_mfma_f32_16x16x32_f16(w1h, p1h, acc[1][1], 0,0,0);
    acc[0][0] = __builtin_amdgcn_mfma_f32_16x16x32_f16(w0h, p0l, acc[0][0], 0,0,0);
    acc[0][1] = __builtin_amdgcn_mfma_f32_16x16x32_f16(w0h, p1l, acc[0][1], 0,0,0);
    acc[1][0] = __builtin_amdgcn_mfma_f32_16x16x32_f16(w1h, p0l, acc[1][0], 0,0,0);
    acc[1][1] = __builtin_amdgcn_mfma_f32_16x16x32_f16(w1h, p1l, acc[1][1], 0,0,0);
    acc[0][0] = __builtin_amdgcn_mfma_f32_16x16x32_f16(w0l, p0h, acc[0][0], 0,0,0);
    acc[0][1] = __builtin_amdgcn_mfma_f32_16x16x32_f16(w0l, p1h, acc[0][1], 0,0,0);
    acc[1][0] = __builtin_amdgcn_mfma_f32_16x16x32_f16(w1l, p0h, acc[1][0], 0,0,0);
    acc[1][1] = __builtin_amdgcn_mfma_f32_16x16x32_f16(w1l, p1h, acc[1][1], 0,0,0);
    __builtin_amdgcn_s_barrier();
    asm volatile("" ::: "memory");
    int kn = (tt+3 < nt) ? (tt+3)*32 : 0;
    stage(bfi, kn);
  }

  int HW = 1<<hwsh;
  int Wi = 1<<wsh;
  int Hi = 1<<(hwsh-wsh);
  #pragma unroll
  for (int ri=0;ri<2;ri++)
  #pragma unroll
  for (int fc=0;fc<2;fc++)
  #pragma unroll
  for (int r=0;r<4;r++){
    int co = bn + wr*32 + ri*16 + (lane>>4)*4 + r;
    int m = bm + wc*32 + fc*16 + (lane&15);
    if (co < N){
      int o = co>>2, p=(co>>1)&1, q=co&1;
      float v = acc[ri][fc][r] + bv[ri][r];
      int bb = m >> hwsh;
      int ij = m & (HW-1);
      int i = ij >> wsh, j = ij & (Wi-1);
      out[(((size_t)bb*Co + o)*(2*Hi) + 2*i+p)*(2*Wi) + 2*j+q] = v;
    }
  }
}

// ---------------- split-K MFMA GEMM, fp32 W and P (in-register hi/lo) ----------------
// slice z handles k in [z*KS, (z+1)*KS); writes fp32 to out[(z*sliceStride+m)*ldc + co], m < Mreal.
__global__ __launch_bounds__(256) void k_gemm_w32s(
    const float* __restrict__ Wf, int ldaW,
    const float* __restrict__ Pf, int ldaP,
    float* __restrict__ out, int N, int KS, int Mreal, int ldc, int sliceStride)
{
  __shared__ __align__(16) float smW[3*2048];
  __shared__ __align__(16) float smP[3*2048];
  int bn = blockIdx.y*64;
  int bm = blockIdx.x*64;
  int kz = blockIdx.z*KS;
  int t = threadIdx.x;
  int lane = t & 63, wv = t >> 6;
  int wr = wv >> 1, wc = wv & 1;

  int wcs = (lane & 7) ^ (lane >> 3);
  size_t gWoff = (size_t)(bn + wv*16 + (lane>>3))*ldaW + wcs*4 + kz;
  size_t gPoff = (size_t)(bm + wv*16 + (lane>>3))*ldaP + wcs*4 + kz;

  int rA = lane & 15, c = lane >> 4;
  int RW0 = wr*32 + rA;  int swzW = RW0 & 7;
  int RP0 = wc*32 + rA;  int swzP = RP0 & 7;
  int cw0 = ((2*c)   ^ swzW)*4;
  int cw1 = ((2*c+1) ^ swzW)*4;
  int pc0 = ((2*c)   ^ swzP)*4;
  int pc1 = ((2*c+1) ^ swzP)*4;

  f32x4 zz = {0.f,0.f,0.f,0.f};
  f32x4 acc[2][2];
  acc[0][0]=zz; acc[0][1]=zz; acc[1][0]=zz; acc[1][1]=zz;

  auto stage = [&](int bfi, int kk){
    GLLDS(Wf + gWoff + kk,                  &smW[bfi*2048 + wv*512]);
    GLLDS(Wf + gWoff + kk + 8*(size_t)ldaW, &smW[bfi*2048 + wv*512 + 256]);
    GLLDS(Pf + gPoff + kk,                  &smP[bfi*2048 + wv*512]);
    GLLDS(Pf + gPoff + kk + 8*(size_t)ldaP, &smP[bfi*2048 + wv*512 + 256]);
  };

  int nt = KS >> 5;
  stage(0, 0);
  stage(1, (nt>1)?32:0);
  stage(2, (nt>2)?64:0);

  for (int tt = 0; tt < nt; ++tt){
    asm volatile("s_waitcnt vmcnt(8)" ::: "memory");
    __builtin_amdgcn_s_barrier();
    asm volatile("" ::: "memory");
    int bfi = tt % 3;
    const float* bW = &smW[bfi*2048];
    const float* bP = &smP[bfi*2048];
    f32x4 a0 = *(const f32x4*)&bW[RW0*32 + cw0];
    f32x4 a1 = *(const f32x4*)&bW[RW0*32 + cw1];
    f32x4 a2 = *(const f32x4*)&bW[RW0*32 + 512 + cw0];
    f32x4 a3 = *(const f32x4*)&bW[RW0*32 + 512 + cw1];
    f32x4 b0 = *(const f32x4*)&bP[RP0*32 + pc0];
    f32x4 b1 = *(const f32x4*)&bP[RP0*32 + pc1];
    f32x4 b2 = *(const f32x4*)&bP[RP0*32 + 512 + pc0];
    f32x4 b3 = *(const f32x4*)&bP[RP0*32 + 512 + pc1];
    f16x8 w0h, w0l, w1h, w1l, p0h, p0l, p1h, p1l;
    #pragma unroll
    for (int j=0;j<4;j++){
      f16 h;
      h=(f16)a0[j]; w0h[j]=h;   w0l[j]  =(f16)(a0[j]-(float)h);
      h=(f16)a1[j]; w0h[4+j]=h; w0l[4+j]=(f16)(a1[j]-(float)h);
      h=(f16)a2[j]; w1h[j]=h;   w1l[j]  =(f16)(a2[j]-(float)h);
      h=(f16)a3[j]; w1h[4+j]=h; w1l[4+j]=(f16)(a3[j]-(float)h);
      h=(f16)b0[j]; p0h[j]=h;   p0l[j]  =(f16)(b0[j]-(float)h);
      h=(f16)b1[j]; p0h[4+j]=h; p0l[4+j]=(f16)(b1[j]-(float)h);
      h=(f16)b2[j]; p1h[j]=h;   p1l[j]  =(f16)(b2[j]-(float)h);
      h=(f16)b3[j]; p1h[4+j]=h; p1l[4+j]=(f16)(b3[j]-(float)h);
    }
    acc[0][0] = __builtin_amdgcn_mfma_f32_16x16x32_f16(w0h, p0h, acc[0][0], 0,0,0);
    acc[0][1] = __builtin_amdgcn_mfma_f32_16x16x32_f16(w0h, p1h, acc[0][1], 0,0,0);
    acc[1][0] = __builtin_amdgcn_mfma_f32_16x16x32_f16(w1h, p0h, acc[1][0], 0,0,0);
    acc[1][1] = __builtin_amdgcn_mfma_f32_16x16x32_f16(w1h, p1h, acc[1][1], 0,0,0);
    acc[0][0] = __builtin_amdgcn_mfma_f32_16x16x32_f16(w0h, p0l, acc[0][0], 0,0,0);
    acc[0][1] = __builtin_amdgcn_mfma_f32_16x16x32_f16(w0h, p1l, acc[0][1], 0,0,0);
    acc[1][0] = __builtin_amdgcn_mfma_f32_16x16x32_f16(w1h, p0l, acc[1][0], 0,0,0);
    acc[1][1] = __builtin_amdgcn_mfma_f32_16x16x32_f16(w1h, p1l, acc[1][1], 0,0,0);
    acc[0][0] = __builtin_amdgcn_mfma_f32_16x16x32_f16(w0l, p0h, acc[0][0], 0,0,0);
    acc[0][1] = __builtin_amdgcn_mfma_f32_16x16x32_f16(w0l, p1h, acc[0][1], 0,0,0);
    acc[1][0] = __builtin_amdgcn_mfma_f32_16x16x32_f16(w1l, p0h, acc[1][0], 0,0,0);
    acc[1][1] = __builtin_amdgcn_mfma_f32_16x16x32_f16(w1l, p1h, acc[1][1], 0,0,0);
    __builtin_amdgcn_s_barrier();
    asm volatile("" ::: "memory");
    int kn = (tt+3 < nt) ? (tt+3)*32 : 0;
    stage(bfi, kn);
  }

  #pragma unroll
  for (int ri=0;ri<2;ri++)
  #pragma unroll
  for (int fc=0;fc<2;fc++)
  #pragma unroll
  for (int r=0;r<4;r++){
    int co = bn + wr*32 + ri*16 + (lane>>4)*4 + r;
    int m  = bm + wc*32 + fc*16 + (lane&15);
    if (m < Mreal)
      out[((size_t)blockIdx.z*sliceStride + m)*ldc + co] = acc[ri][fc][r];
  }
}

// ---------------- dt projection ----------------
__global__ __launch_bounds__(256) void k_dt(
    const float* __restrict__ xdp, const float* __restrict__ dtW,
    const float* __restrict__ dtB, float* __restrict__ dtb)
{
  __shared__ float smP[64*36];
  __shared__ float smW[64*36];
  int bn = blockIdx.x*64;
  int bm = blockIdx.y*64;
  int t = threadIdx.x, lane = t&63, wv = t>>6, wr = wv>>1, wc = wv&1;
  {
    int row = t>>2, c0 = (t&3)*8;
    #pragma unroll
    for (int j=0;j<8;j++){
      int cc = c0+j;
      float pv = 0.f;
      #pragma unroll
      for (int s=0;s<4;s++) pv += xdp[((size_t)(s*192) + bm+row)*64 + cc];
      smP[row*36 + cc] = pv;
      smW[row*36 + cc] = dtW[(size_t)(bn+row)*32 + cc];
    }
  }
  __syncthreads();
  int rA = lane&15, c = lane>>4;
  int c8 = c*8;
  f32x4 a0 = *(const f32x4*)&smW[(wr*32+rA)*36 + c8];
  f32x4 a1 = *(const f32x4*)&smW[(wr*32+rA)*36 + c8+4];
  f32x4 a2 = *(const f32x4*)&smW[(wr*32+16+rA)*36 + c8];
  f32x4 a3 = *(const f32x4*)&smW[(wr*32+16+rA)*36 + c8+4];
  f32x4 b0 = *(const f32x4*)&smP[(wc*32+rA)*36 + c8];
  f32x4 b1 = *(const f32x4*)&smP[(wc*32+rA)*36 + c8+4];
  f32x4 b2 = *(const f32x4*)&smP[(wc*32+16+rA)*36 + c8];
  f32x4 b3 = *(const f32x4*)&smP[(wc*32+16+rA)*36 + c8+4];
  f16x8 w0h, w0l, w1h, w1l, p0h, p0l, p1h, p1l;
  #pragma unroll
  for (int j=0;j<4;j++){
    f16 h;
    h=(f16)a0[j]; w0h[j]=h;   w0l[j]  =(f16)(a0[j]-(float)h);
    h=(f16)a1[j]; w0h[4+j]=h; w0l[4+j]=(f16)(a1[j]-(float)h);
    h=(f16)a2[j]; w1h[j]=h;   w1l[j]  =(f16)(a2[j]-(float)h);
    h=(f16)a3[j]; w1h[4+j]=h; w1l[4+j]=(f16)(a3[j]-(float)h);
    h=(f16)b0[j]; p0h[j]=h;   p0l[j]  =(f16)(b0[j]-(float)h);
    h=(f16)b1[j]; p0h[4+j]=h; p0l[4+j]=(f16)(b1[j]-(float)h);
    h=(f16)b2[j]; p1h[j]=h;   p1l[j]  =(f16)(b2[j]-(float)h);
    h=(f16)b3[j]; p1h[4+j]=h; p1l[4+j]=(f16)(b3[j]-(float)h);
  }
  f32x4 zz = {0.f,0.f,0.f,0.f};
  f32x4 acc[2][2];
  acc[0][0]=zz; acc[0][1]=zz; acc[1][0]=zz; acc[1][1]=zz;
  acc[0][0] = __builtin_amdgcn_mfma_f32_16x16x32_f16(w0h, p0h, acc[0][0], 0,0,0);
  acc[0][1] = __builtin_amdgcn_mfma_f32_16x16x32_f16(w0h, p1h, acc[0][1], 0,0,0);
  acc[1][0] = __builtin_amdgcn_mfma_f32_16x16x32_f16(w1h, p0h, acc[1][0], 0,0,0);
  acc[1][1] = __builtin_amdgcn_mfma_f32_16x16x32_f16(w1h, p1h, acc[1][1], 0,0,0);
  acc[0][0] = __builtin_amdgcn_mfma_f32_16x16x32_f16(w0h, p0l, acc[0][0], 0,0,0);
  acc[0][1] = __builtin_amdgcn_mfma_f32_16x16x32_f16(w0h, p1l, acc[0][1], 0,0,0);
  acc[1][0] = __builtin_amdgcn_mfma_f32_16x16x32_f16(w1h, p0l, acc[1][0], 0,0,0);
  acc[1][1] = __builtin_amdgcn_mfma_f32_16x16x32_f16(w1h, p1l, acc[1][1], 0,0,0);
  acc[0][0] = __builtin_amdgcn_mfma_f32_16x16x32_f16(w0l, p0h, acc[0][0], 0,0,0);
  acc[0][1] = __builtin_amdgcn_mfma_f32_16x16x32_f16(w0l, p1h, acc[0][1], 0,0,0);
  acc[1][0] = __builtin_amdgcn_mfma_f32_16x16x32_f16(w1l, p0h, acc[1][0], 0,0,0);
  acc[1][1] = __builtin_amdgcn_mfma_f32_16x16x32_f16(w1l, p1h, acc[1][1], 0,0,0);
  #pragma unroll
  for (int ri=0;ri<2;ri++)
  #pragma unroll
  for (int fc=0;fc<2;fc++)
  #pragma unroll
  for (int r=0;r<4;r++){
    int co = bn + wr*32 + ri*16 + (lane>>4)*4 + r;
    int m  = bm + wc*32 + fc*16 + (lane&15);
    if (m < 130)
      dtb[(size_t)m*1024 + co] = softplusf(acc[ri][fc][r] + dtB[co]);
  }
}

__global__ void k_maxpool2(const float* __restrict__ in, float* __restrict__ out, int BC, int H, int W){
  int Ho=H/2, Wo=W/2;
  int idx = blockIdx.x*blockDim.x + threadIdx.x;
  if (idx >= BC*Ho*Wo) return;
  int xo = idx % Wo; int yo = (idx / Wo) % Ho; int c = idx / (Wo*Ho);
  const float* p = in + ((size_t)c*H + 2*yo)*W + 2*xo;
  out[idx] = fmaxf(fmaxf(p[0],p[1]), fmaxf(p[W],p[W+1]));
}

// ---------------- Mamba ----------------
__global__ void k_build_tok(const float* __restrict__ p4, const float* __restrict__ cls,
                            float* __restrict__ hidp, float* __restrict__ residual){
  int idx = blockIdx.x*blockDim.x+threadIdx.x;
  if (idx >= 2*65*512) return;
  int d = idx % 512; int l = (idx/512)%65; int b = idx/(512*65);
  float v = (l==0) ? cls[d] : p4[((size_t)b*512+d)*64 + (l-1)];
  int row = b*65 + l;
  residual[(size_t)row*512 + d] = v;
  hidp[(size_t)row*512 + d] = v;
  #pragma unroll
  for (int s=1;s<8;s++) hidp[((size_t)(s*192) + row)*512 + d] = 0.f;
}

__global__ void k_add_ln(float* __restrict__ residual, const float* __restrict__ hidp,
                         const float* __restrict__ nw, const float* __restrict__ nb,
                         float* __restrict__ hs){
  int row = blockIdx.x;
  int t = threadIdx.x;
  __shared__ float red[256];
  size_t base = (size_t)row*512;
  float h0 = 0.f, h1 = 0.f;
  #pragma unroll
  for (int s=0;s<8;s++){
    h0 += hidp[((size_t)(s*192) + row)*512 + t];
    h1 += hidp[((size_t)(s*192) + row)*512 + 256 + t];
  }
  float v0 = residual[base + t]       + h0;
  float v1 = residual[base + 256 + t] + h1;
  residual[base+t]=v0; residual[base+256+t]=v1;
  red[t]=v0+v1; __syncthreads();
  for(int o=128;o>0;o>>=1){ if(t<o) red[t]+=red[t+o]; __syncthreads(); }
  float mean = red[0]/512.f; __syncthreads();
  float d0=v0-mean, d1=v1-mean;
  red[t]=d0*d0+d1*d1; __syncthreads();
  for(int o=128;o>0;o>>=1){ if(t<o) red[t]+=red[t+o]; __syncthreads(); }
  float rstd = rsqrtf(red[0]/512.f + 1e-5f);
  hs[base+t]     = d0*rstd*nw[t]     + nb[t];
  hs[base+256+t] = d1*rstd*nw[256+t] + nb[256+t];
}

__global__ void k_conv1d_silu(const float* __restrict__ xzp, const float* __restrict__ cw,
                              const float* __restrict__ cb, float* __restrict__ xc){
  int d = blockIdx.x*blockDim.x + threadIdx.x;
  int l = blockIdx.y, b = blockIdx.z;
  if (d>=1024) return;
  float acc = cb[d];
  #pragma unroll
  for(int k=0;k<4;k++){
    int lp = l-3+k;
    if (lp>=0){
      size_t r = (size_t)(b*65+lp);
      float xzv = xzp[r*2048 + d] + xzp[(r + 192)*2048 + d];
      acc = fmaf(xzv, cw[d*4+k], acc);
    }
  }
  xc[((size_t)(b*65+l))*1024 + d] = siluf(acc);
}

__global__ void k_scan(const float* __restrict__ dt, const float* __restrict__ xc,
                       const float* __restrict__ xdp, const float* __restrict__ xzp,
                       const float* __restrict__ Alog, const float* __restrict__ Dp,
                       float* __restrict__ gt){
  int gid = blockIdx.x*blockDim.x + threadIdx.x;
  if (gid >= 2*1024*16) return;
  int n = gid & 15;
  int d = (gid >> 4) & 1023;
  int b = gid >> 14;
  float A = -expf(Alog[d*16+n]);
  float Dv = Dp[d];
  float h = 0.f;
  for (int l=0;l<65;l++){
    size_t r = (size_t)(b*65+l);
    float dtv = dt[r*1024+d];
    float xcv = xc[r*1024+d];
    float Bn = 0.f, Cn = 0.f;
    #pragma unroll
    for (int s=0;s<4;s++){
      Bn += xdp[((size_t)(s*192) + r)*64 + 32 + n];
      Cn += xdp[((size_t)(s*192) + r)*64 + 48 + n];
    }
    h = fmaf(expf(dtv*A), h, dtv*xcv*Bn);
    float y = h*Cn;
    y += __shfl_xor(y, 1); y += __shfl_xor(y, 2);
    y += __shfl_xor(y, 4); y += __shfl_xor(y, 8);
    if (n==0){
      float zv = xzp[r*2048 + 1024 + d] + xzp[(r + 192)*2048 + 1024 + d];
      gt[r*1024+d] = (y + Dv*xcv) * siluf(zv);
    }
  }
}

__global__ void k_xsp(const float* __restrict__ hidp, float* __restrict__ xsp){
  int idx = blockIdx.x*blockDim.x+threadIdx.x;
  if (idx>=2*512*64) return;
  int j = idx & 63; int c = (idx>>6)&511; int b = idx>>15;
  int row = b*65 + 1 + j;
  float v = 0.f;
  #pragma unroll
  for (int s=0;s<8;s++) v += hidp[((size_t)(s*192) + row)*512 + c];
  xsp[idx] = v;
}

__global__ void k_conv1x1(const float* __restrict__ in, const float* __restrict__ w,
                          const float* __restrict__ bias, float* __restrict__ out){
  int hw = blockIdx.x*blockDim.x+threadIdx.x; if (hw>=128*128) return;
  int o = blockIdx.y, b = blockIdx.z;
  float acc = bias[o];
  #pragma unroll
  for(int c=0;c<32;c++) acc = fmaf(in[((size_t)(b*32+c))*16384 + hw], w[o*32+c], acc);
  out[((size_t)(b*4+o))*16384 + hw] = acc;
}

__global__ void k_resize16(const float* __restrict__ in, float* __restrict__ out){
  size_t idx = (size_t)blockIdx.x*blockDim.x + threadIdx.x;
  if (idx >= (size_t)2*4*2048*2048) return;
  int x = idx & 2047; int y = (int)((idx>>11)&2047); int c = (int)(idx>>22);
  float sx = ((float)x+0.5f)*(1.f/16.f) - 0.5f;
  float sy = ((float)y+0.5f)*(1.f/16.f) - 0.5f;
  int x0 = (int)floorf(sx); float fx = sx-(float)x0;
  int y0 = (int)floorf(sy); float fy = sy-(float)y0;
  int x0c = max(x0,0), x1c = min(x0+1,127);
  int y0c = max(y0,0), y1c = min(y0+1,127);
  const float* p = in + (size_t)c*16384;
  float v00=p[y0c*128+x0c], v01=p[y0c*128+x1c], v10=p[y1c*128+x0c], v11=p[y1c*128+x1c];
  out[idx] = (1.f-fy)*((1.f-fx)*v00 + fx*v01) + fy*((1.f-fx)*v10 + fx*v11);
}

// ---------------- host ----------------
#define MAX_A_ELEMS 524288

extern "C" void kernel_launch(void* const* d_in, const int* in_sizes, int n_in,
                              void* d_out, int out_size, void* d_ws, size_t ws_size,
                              hipStream_t stream) {
  const float* x        = (const float*)d_in[0];
  const float* masks    = (const float*)d_in[1];
  const float* ew1[4] = {(const float*)d_in[2],(const float*)d_in[6],(const float*)d_in[10],(const float*)d_in[14]};
  const float* eb1[4] = {(const float*)d_in[3],(const float*)d_in[7],(const float*)d_in[11],(const float*)d_in[15]};
  const float* ew2[4] = {(const float*)d_in[4],(const float*)d_in[8],(const float*)d_in[12],(const float*)d_in[16]};
  const float* eb2[4] = {(const float*)d_in[5],(const float*)d_in[9],(const float*)d_in[13],(const float*)d_in[17]};
  const float* cls      = (const float*)d_in[18];
  const float* norm_w   = (const float*)d_in[19];
  const float* norm_b   = (const float*)d_in[20];
  const float* in_proj  = (const float*)d_in[21];
  const float* conv1d_w = (const float*)d_in[22];
  const float* conv1d_b = (const float*)d_in[23];
  const float* x_proj   = (const float*)d_in[24];
  const float* dt_w     = (const float*)d_in[25];
  const float* dt_b     = (const float*)d_in[26];
  const float* A_log    = (const float*)d_in[27];
  const float* D_ssm    = (const float*)d_in[28];
  const float* out_proj = (const float*)d_in[29];
  const float* dup_w[4] = {(const float*)d_in[30],(const float*)d_in[36],(const float*)d_in[42],(const float*)d_in[48]};
  const float* dup_b[4] = {(const float*)d_in[31],(const float*)d_in[37],(const float*)d_in[43],(const float*)d_in[49]};
  const float* dw1[4]   = {(const float*)d_in[32],(const float*)d_in[38],(const float*)d_in[44],(const float*)d_in[50]};
  const float* db1[4]   = {(const float*)d_in[33],(const float*)d_in[39],(const float*)d_in[45],(const float*)d_in[51]};
  const float* dw2[4]   = {(const float*)d_in[34],(const float*)d_in[40],(const float*)d_in[46],(const float*)d_in[52]};
  const float* db2[4]   = {(const float*)d_in[35],(const float*)d_in[41],(const float*)d_in[47],(const float*)d_in[53]};
  const float* final_w  = (const float*)d_in[54];
  const float* final_b  = (const float*)d_in[55];
  float* out = (float*)d_out;

  float* W = (float*)d_ws;
  size_t off = 0;
  auto alloc = [&](size_t n){ float* p = W + off; off += n; return p; };

  float* Tre = alloc(32768);  float* Tim = alloc(32768);
  float* Fre = alloc(32768);  float* Fim = alloc(32768);
  float* Gre = alloc(196608); float* Gim = alloc(196608);
  float* xfreq = alloc(98304);
  float* tmpA = alloc(2097152);
  float* e1 = alloc(2097152);
  float* p1 = alloc(524288);
  float* e2 = alloc(1048576);
  float* p2 = alloc(262144);
  float* e3 = alloc(524288);
  float* p3 = alloc(131072);
  float* e4 = alloc(262144);
  float* p4 = alloc(65536);
  float* residual = alloc(66560);
  float* xsp = alloc(65536);
  float* tmpB = alloc(1048576);
  float* d4 = alloc(131072);
  float* d3 = alloc(262144);
  float* d2 = alloc(524288);
  float* d1 = alloc(1048576);
  float* fin = alloc(131072);
  (void)ws_size; (void)n_in; (void)in_sizes; (void)out_size;

  // ---- weight descriptor table (f16 conversions; small-conv entries unused but harmless) ----
  WAll wa;
  {
    const float* s[NWD] = { ew1[0], ew2[0], ew1[1], ew2[1], ew1[2], ew2[2], ew1[3], ew2[3],
                            dw1[0], dw2[0], dw1[1], dw2[1], dw1[2], dw2[2], dw1[3], dw2[3],
                            dup_w[0], dup_w[1], dup_w[2], dup_w[3] };
    const int N_[NWD]  = {64,64,128,128,256,256,512,512, 256,256,128,128,64,64,32,32, 1024,512,256,128};
    const int CI_[NWD] = {3,64,64,128,128,256,256,512, 768,256,384,128,192,64,96,32, 512,256,128,64};
    const int U_[NWD]  = {0,0,0,0,0,0,0,0, 0,0,0,0,0,0,0,0, 256,128,64,32};
    int cacc = 0;
    for (int i=0;i<NWD;i++){
      wa.src[i]=s[i]; wa.N[i]=N_[i]; wa.up[i]=U_[i]; wa.ci[i]=CI_[i];
      int cip = (CI_[i]+31)&~31;
      wa.cip[i] = cip;
      wa.Kp[i] = U_[i] ? CI_[i] : 9*cip;
      wa.cum[i]=cacc;
      int Np=(N_[i]+63)&~63;
      cacc += Np*wa.Kp[i];
    }
    wa.cum[NWD]=cacc;
  }
  int wtotal = wa.cum[NWD];

  // ---- scratch in d_out (all dead before k_resize16 rewrites it) ----
  f16* q = (f16*)d_out;
  f16* Ahi = q; q += MAX_A_ELEMS;
  f16* Alo = q; q += MAX_A_ELEMS;
  f16* Ball_h = q; q += wtotal;
  f16* Ball_l = q; q += wtotal;
  float* fb = (float*)q;
  size_t foff = 0;
  auto falloc = [&](size_t n){ float* p = fb + foff; foff += n; return p; };
  float* convpart = falloc(2097152);
  float* Af32 = falloc(7340032);          // im2col fp32 A (max d3a: 2048 x 3456)
  float* xzp  = falloc(2*192*2048);
  float* xdp  = falloc(4*192*64);
  float* hidp = falloc(8*192*512);
  float* hs   = falloc(192*512);
  float* xc   = falloc(192*1024);
  float* gt   = falloc(192*1024);
  float* dtb  = falloc(192*1024);

  hipLaunchKernelGGL(k_wcvt_all, dim3((wtotal+255)/256), dim3(256), 0, stream, wa, wtotal, Ball_h, Ball_l);

  // ---- frequency band split ----
  hipLaunchKernelGGL(k_dft_rows, dim3(128,2), dim3(128), 0, stream, x, Tre, Tim);
  hipLaunchKernelGGL(k_dft_cols, dim3(128,2), dim3(128), 0, stream, Tre, Tim, Fre, Fim);
  hipLaunchKernelGGL(k_idft_cols, dim3(128,3,2), dim3(128), 0, stream, Fre, Fim, masks, Gre, Gim);
  hipLaunchKernelGGL(k_idft_rows, dim3(128,3,2), dim3(128), 0, stream, Gre, Gim, xfreq);

  auto ctz = [](int v){ int s=0; while(!(v&1)){v>>=1;s++;} return s; };
  // big-image convs: proven implicit-GEMM (S=1)
  auto conv_ig = [&](const float* i1,int C1,const float* i2,int C2,
                     int widx, const float* bias, float* o, int Co, int H){
    int Wd = H;
    int Ci = C1+C2, Cip = (Ci+31)&~31;
    int M = 2*H*Wd, Np = (Co+63)&~63;
    int wsh = ctz(Wd), hwsh = ctz(H*Wd);
    int civ = Ci < 32 ? Ci : 32;
    const f16* bh = Ball_h + wa.cum[widx];
    const f16* bl = Ball_l + wa.cum[widx];
    dim3 g(M/64, Np/64);
    if (Wd >= 64)
      hipLaunchKernelGGL((k_conv_ig<25>), g, dim3(256), 0, stream, i1,C1,i2,C2,bh,bl,bias,o,Co,H,Wd,wsh,hwsh,Cip,civ);
    else if (Wd == 32)
      hipLaunchKernelGGL((k_conv_ig<17>), g, dim3(256), 0, stream, i1,C1,i2,C2,bh,bl,bias,o,Co,H,Wd,wsh,hwsh,Cip,civ);
    else
      hipLaunchKernelGGL((k_conv_ig<14>), g, dim3(256), 0, stream, i1,C1,i2,C2,bh,bl,bias,o,Co,H,Wd,wsh,hwsh,Cip,civ);
  };
  // small-image convs: fp32 im2col + split-K MFMA GEMM (raw fp32 weights) + creduce
  auto conv_sk = [&](const float* i1,int C1,const float* i2,int C2,
                     const float* wraw, const float* bias, float* o, int Co, int H, int S){
    int Wd = H;
    int Ci = C1+C2, K = Ci*9;
    int M = 2*H*Wd;
    int wsh = ctz(Wd), hwsh = ctz(H*Wd);
    hipLaunchKernelGGL(k_im2col32, dim3((K+255)/256, M), dim3(256), 0, stream,
                       i1, C1, i2, C2, H, Wd, wsh, hwsh, K, Af32);
    int KS = K / S;
    hipLaunchKernelGGL(k_gemm_w32s, dim3(M/64, Co/64, S), dim3(256), 0, stream,
                       wraw, K, Af32, K, convpart, Co, KS, M, Co, M);
    hipLaunchKernelGGL(k_creduce, dim3((M*Co+255)/256), dim3(256), 0, stream,
                       convpart, bias, o, M, Co, ctz(M), ctz(Co), hwsh, S);
  };
  auto up_bf = [&](const float* in, int widx, const float* bias, float* o,
                   int Ci,int Co,int Hi){
    int Kp=Ci, N=4*Co;
    int M=2*Hi*Hi;
    int wsh=ctz(Hi), hwsh=ctz(Hi*Hi);
    const f16* bh = Ball_h + wa.cum[widx];
    const f16* bl = Ball_l + wa.cum[widx];
    hipLaunchKernelGGL(k_im2col, dim3((Kp+255)/256, M), dim3(256), 0, stream,
                       in, Ci, Hi, Hi, wsh, hwsh, Ci, Kp, Ahi, Alo);
    hipLaunchKernelGGL(k_gemm_hl, dim3(M/64, N/64), dim3(256), 0, stream,
                       bh, bl, Ahi, Alo, bias, o, N, Kp, wsh, hwsh, Co);
  };

  // ---- encoder ----
  conv_ig(xfreq,3,  nullptr,0, 0, eb1[0], tmpA, 64, 128);
  conv_ig(tmpA,64,  nullptr,0, 1, eb2[0], e1,   64, 128);
  hipLaunchKernelGGL(k_maxpool2, dim3((2*64*64*64+255)/256), dim3(256), 0, stream, e1, p1, 2*64, 128,128);
  conv_ig(p1,64,    nullptr,0, 2, eb1[1], tmpA, 128, 64);
  conv_ig(tmpA,128, nullptr,0, 3, eb2[1], e2,   128, 64);
  hipLaunchKernelGGL(k_maxpool2, dim3((2*128*32*32+255)/256), dim3(256), 0, stream, e2, p2, 2*128, 64,64);
  conv_sk(p2,128,   nullptr,0, ew1[2], eb1[2], tmpA, 256, 32, 4);
  conv_sk(tmpA,256, nullptr,0, ew2[2], eb2[2], e3,   256, 32, 4);
  hipLaunchKernelGGL(k_maxpool2, dim3((2*256*16*16+255)/256), dim3(256), 0, stream, e3, p3, 2*256, 32,32);
  conv_sk(p3,256,   nullptr,0, ew1[3], eb1[3], tmpA, 512, 16, 8);
  conv_sk(tmpA,512, nullptr,0, ew2[3], eb2[3], e4,   512, 16, 8);
  hipLaunchKernelGGL(k_maxpool2, dim3((2*512*8*8+255)/256), dim3(256), 0, stream, e4, p4, 2*512, 16,16);

  // ---- mamba stack ----
  hipLaunchKernelGGL(k_build_tok, dim3((2*65*512+255)/256), dim3(256), 0, stream, p4, cls, hidp, residual);
  for (int l=0;l<24;l++){
    const float* nw   = norm_w   + (size_t)l*512;
    const float* nb   = norm_b   + (size_t)l*512;
    const float* inW  = in_proj  + (size_t)l*2048*512;
    const float* cw   = conv1d_w + (size_t)l*1024*4;
    const float* cb   = conv1d_b + (size_t)l*1024;
    const float* xpW  = x_proj   + (size_t)l*64*1024;
    const float* dtW  = dt_w     + (size_t)l*1024*32;
    const float* dtB  = dt_b     + (size_t)l*1024;
    const float* Alg  = A_log    + (size_t)l*1024*16;
    const float* Dp   = D_ssm    + (size_t)l*1024;
    const float* outW = out_proj + (size_t)l*512*1024;

    hipLaunchKernelGGL(k_add_ln, dim3(130), dim3(256), 0, stream, residual, hidp, nw, nb, hs);
    hipLaunchKernelGGL(k_gemm_w32s, dim3(3,32,2), dim3(256), 0, stream,
                       inW, 512, hs, 512, xzp, 2048, 256, 130, 2048, 192);
    hipLaunchKernelGGL(k_conv1d_silu, dim3(4,65,2), dim3(256), 0, stream, xzp, cw, cb, xc);
    hipLaunchKernelGGL(k_gemm_w32s, dim3(3,1,4), dim3(256), 0, stream,
                       xpW, 1024, xc, 1024, xdp, 64, 256, 130, 64, 192);
    hipLaunchKernelGGL(k_dt, dim3(16,3), dim3(256), 0, stream, xdp, dtW, dtB, dtb);
    hipLaunchKernelGGL(k_scan, dim3(128), dim3(256), 0, stream, dtb, xc, xdp, xzp, Alg, Dp, gt);
    hipLaunchKernelGGL(k_gemm_w32s, dim3(3,8,8), dim3(256), 0, stream,
                       outW, 1024, gt, 1024, hidp, 512, 128, 130, 512, 192);
  }
  hipLaunchKernelGGL(k_xsp, dim3((2*512*64+255)/256), dim3(256), 0, stream, hidp, xsp);

  // ---- decoder ----
  up_bf(xsp, 16, dup_b[0], tmpB, 512, 256, 8);
  conv_sk(e4,512, tmpB,256, dw1[0], db1[0], tmpA, 256, 16, 8);
  conv_sk(tmpA,256, nullptr,0, dw2[0], db2[0], d4, 256, 16, 8);
  up_bf(d4, 17, dup_b[1], tmpB, 256, 128, 16);
  conv_sk(e3,256, tmpB,128, dw1[1], db1[1], tmpA, 128, 32, 4);
  conv_sk(tmpA,128, nullptr,0, dw2[1], db2[1], d3, 128, 32, 4);
  up_bf(d3, 18, dup_b[2], tmpB, 128, 64, 32);
  conv_ig(e2,128, tmpB,64, 12, db1[2], tmpA, 64, 64);
  conv_ig(tmpA,64, nullptr,0, 13, db2[2], d2, 64, 64);
  up_bf(d2, 19, dup_b[3], tmpB, 64, 32, 64);
  conv_ig(e1,64, tmpB,32, 14, db1[3], tmpA, 32, 128);
  conv_ig(tmpA,32, nullptr,0, 15, db2[3], d1, 32, 128);

  // ---- head ----
  hipLaunchKernelGGL(k_conv1x1, dim3((16384+255)/256, 4, 2), dim3(256), 0, stream, d1, final_w, final_b, fin);
  hipLaunchKernelGGL(k_resize16, dim3((size_t)(2*4*2048*2048)/256), dim3(256), 0, stream, fin, out);
}